// Round 2
// baseline (491.370 us; speedup 1.0000x reference)
//
#include <hip/hip_runtime.h>

#define SRF 44100.0f
#define TWO_PI 6.283185307179586f
#define W 882
#define NB 9510
#define MCH 30
#define G_CH 317
#define NS 8388608
#define REMSTART 8387820
#define REMN 788
#define BRL 128
#define BRC 65536
#define SCAN_R 64

// ---- ws float layout ----
#define WS_D2 0
#define WS_FA 1
#define WS_B0 2
#define WS_B1 3
#define WS_B2 4
#define WS_A1 5
#define WS_A2 6
#define WS_INVA 7
#define WS_INVR 8
#define WS_SUS 9
#define WS_AMP 10
#define WS_T 16
#define WS_M 24                       // 10 matrices x 4
#define WS_CW0 64                     // 882
#define WS_DELTA 1024                 // G_CH*W = 279594
#define WS_CWINIT (WS_DELTA + G_CH*W) // 279594 -> end 560212 floats (~2.25MB)
// BR arrays reuse the delta region (KS finished before BR starts)
#define WS_BRD  WS_DELTA              // 2*BRC
#define WS_BRS  (WS_BRD + 2*BRC)      // 2*BRC
#define WS_XT1  (WS_BRS + 2*BRC)      // BRC
#define WS_XT2  (WS_XT1 + BRC)        // BRC

// ---------------- K0: coefficients + wavetable biquads (serial, tiny) -------
__global__ void k0_setup(const float* __restrict__ wt,
                         const float* __restrict__ h,
                         const float* __restrict__ envp,
                         const float* __restrict__ lp2c,
                         float* __restrict__ ws) {
    if (blockIdx.x != 0 || threadIdx.x != 0) return;
    float h0=h[0], h1=h[1], h2=h[2], h3=h[3], h4=h[4], h5=h[5], h6=h[6];
    float decay = fminf(fmaxf(h0 / 10.0f + 0.9f, 0.9f), 0.999f);
    ws[WS_D2] = decay * 0.5f;
    ws[WS_FA] = h3;

    // lowpass #1 on wavetable -> ws[WS_CW0..]
    {
        float freq = fminf(fmaxf(h1 * (SRF/4.0f), 100.0f), SRF/2.0f - 1.0f);
        float q    = fminf(fmaxf(h2, 0.1f), 0.999f);
        float w0 = TWO_PI * freq / SRF;
        float sw = sinf(w0), cw = cosf(w0);
        float alpha = sw / (2.0f * q);
        float b0 = (1.0f - cw) * 0.5f, b1 = 1.0f - cw, b2 = b0;
        float a0 = 1.0f + alpha, a1 = -2.0f * cw, a2 = 1.0f - alpha;
        float b0n=b0/a0, b1n=b1/a0, b2n=b2/a0, a1n=a1/a0, a2n=a2/a0;
        float x1=0.f,x2=0.f,y1=0.f,y2=0.f;
        for (int n=0;n<W;n++){
            float xn = wt[n];
            float yn = b0n*xn + b1n*x1 + b2n*x2 - a1n*y1 - a2n*y2;
            x2=x1; x1=xn; y2=y1; y1=yn;
            ws[WS_CW0+n] = yn;
        }
    }
    // lowpass #2 (in place)
    {
        float freq = 100.0f + lp2c[0]*8000.0f;
        float q = 0.707f;
        float w0 = TWO_PI * freq / SRF;
        float sw = sinf(w0), cw = cosf(w0);
        float alpha = sw / (2.0f * q);
        float b0 = (1.0f - cw) * 0.5f, b1 = 1.0f - cw, b2 = b0;
        float a0 = 1.0f + alpha, a1 = -2.0f * cw, a2 = 1.0f - alpha;
        float b0n=b0/a0, b1n=b1/a0, b2n=b2/a0, a1n=a1/a0, a2n=a2/a0;
        float x1=0.f,x2=0.f,y1=0.f,y2=0.f;
        for (int n=0;n<W;n++){
            float xn = ws[WS_CW0+n];
            float yn = b0n*xn + b1n*x1 + b2n*x2 - a1n*y1 - a2n*y2;
            x2=x1; x1=xn; y2=y1; y1=yn;
            ws[WS_CW0+n] = yn;
        }
    }
    // bandreject coefs + scan matrices
    {
        float freq = fminf(fmaxf(h5*(SRF/4.0f), 100.0f), SRF/2.0f - 1.0f);
        float q = fminf(fmaxf(h6, 0.1f), 0.999f);
        float w0 = TWO_PI * freq / SRF;
        float sw = sinf(w0), cw = cosf(w0);
        float alpha = sw / (2.0f * q);
        float b0 = 1.0f, b1 = -2.0f*cw, b2 = 1.0f;
        float a0 = 1.0f + alpha, a1 = -2.0f*cw, a2 = 1.0f - alpha;
        ws[WS_B0]=b0/a0; ws[WS_B1]=b1/a0; ws[WS_B2]=b2/a0;
        float A1=a1/a0, A2=a2/a0;
        ws[WS_A1]=A1; ws[WS_A2]=A2;
        // A = [[-A1,-A2],[1,0]]; T = A^128 (7 squarings)
        float t00=-A1, t01=-A2, t10=1.0f, t11=0.0f;
        for (int k=0;k<7;k++){
            float na=t00*t00+t01*t10, nb=t00*t01+t01*t11;
            float nc=t10*t00+t11*t10, nd=t10*t01+t11*t11;
            t00=na;t01=nb;t10=nc;t11=nd;
        }
        ws[WS_T+0]=t00; ws[WS_T+1]=t01; ws[WS_T+2]=t10; ws[WS_T+3]=t11;
        // T64 = T^64 (6 more squarings)
        for (int k=0;k<6;k++){
            float na=t00*t00+t01*t10, nb=t00*t01+t01*t11;
            float nc=t10*t00+t11*t10, nd=t10*t01+t11*t11;
            t00=na;t01=nb;t10=nc;t11=nd;
        }
        // M[k] = T64^(2^k)
        for (int k=0;k<10;k++){
            ws[WS_M+4*k+0]=t00; ws[WS_M+4*k+1]=t01;
            ws[WS_M+4*k+2]=t10; ws[WS_M+4*k+3]=t11;
            float na=t00*t00+t01*t10, nb=t00*t01+t01*t11;
            float nc=t10*t00+t11*t10, nd=t10*t01+t11*t11;
            t00=na;t01=nb;t10=nc;t11=nd;
        }
    }
    // envelope
    {
        float nF = (float)NS;
        float attack  = 1.0f + envp[0]*0.1f*nF;
        float release = 1.0f + envp[2]*0.1f*nF;
        ws[WS_INVA] = 1.0f/attack;
        ws[WS_INVR] = 1.0f/release;
        ws[WS_SUS]  = fminf(fmaxf(envp[1], 0.0f), 1.0f);
        ws[WS_AMP]  = h4;
    }
}

// ---------------- K1: KS pass A — zero-state chunk deltas -------------------
__global__ __launch_bounds__(896) void k1_ksA(const float* __restrict__ fb,
                                              float* __restrict__ ws) {
    __shared__ float sv[W];
    const int i = threadIdx.x;
    const int g = blockIdx.x;
    const float d2 = ws[WS_D2], fa = ws[WS_FA];
    float z = 0.0f;
    const float* fbp = fb + (long)g*MCH*W + i;
    float cur = (i < W) ? fbp[0] : 0.0f;
    for (int j = 0; j < MCH; j++) {
        float nxt = 0.0f;
        if (j+1 < MCH && i < W) nxt = fbp[(long)(j+1)*W];
        float v = 0.0f;
        if (i < W) { v = z + tanhf(fa*cur); sv[i] = v; }
        __syncthreads();
        if (i < W) {
            float vp = sv[(i==0) ? (W-1) : (i-1)];
            z = d2 * (v + vp);
        }
        __syncthreads();
        cur = nxt;
    }
    if (i < W) ws[WS_DELTA + g*W + i] = z;
}

// ---------------- K2: KS pass B — serial chunk-state combine ----------------
// c_{g+1}[i] = sum_{j=0..30} w[j]*c_g[(i-j) mod W] + delta_g[i]
// w = impulse response of 30 steps of S. Phys LDS layout: logical-32..883
__global__ __launch_bounds__(256) void k2_ksB(float* __restrict__ ws) {
    __shared__ float ubuf[2][W];
    __shared__ float wvs[MCH+1];
    __shared__ float cbuf[2][920];
    const int tid = threadIdx.x;
    const float d2 = ws[WS_D2];

    // weights via impulse iteration
    for (int i = tid; i < W; i += 256) ubuf[0][i] = (i==0)?1.0f:0.0f;
    __syncthreads();
    int p = 0;
    for (int s = 0; s < MCH; s++) {
        for (int i = tid; i < W; i += 256) {
            float a = ubuf[p][i];
            float b = ubuf[p][(i==0)?(W-1):(i-1)];
            ubuf[1-p][i] = d2*(a+b);
        }
        __syncthreads();
        p ^= 1;
    }
    if (tid <= MCH) wvs[tid] = ubuf[p][tid];
    // init c = cw0 (with mirrors), store cwinit[0]
    for (int i = tid; i < W; i += 256) {
        float c0 = ws[WS_CW0 + i];
        cbuf[0][i+32] = c0;
        ws[WS_CWINIT + i] = c0;
        if (i >= W-32) cbuf[0][i+32-W] = c0;   // phys 0..31 = logical 850..881
        if (i < 2)     cbuf[0][i+32+W] = c0;   // phys 914,915 = logical 0,1
    }
    __syncthreads();

    float wvr[MCH+1];
    #pragma unroll
    for (int j = 0; j <= MCH; j++) wvr[j] = wvs[j];

    const int t = tid;
    const bool act = (t < 221);
    int pb = 0;
    float dn[4];
    if (act) {
        #pragma unroll
        for (int k=0;k<4;k++){ int o=4*t+k; dn[k] = (o<W)? ws[WS_DELTA + o] : 0.0f; }
    }
    for (int g = 0; g < G_CH-1; g++) {
        float s[4]; float cc[36];
        if (act) {
            float dcur[4];
            #pragma unroll
            for (int k=0;k<4;k++) dcur[k]=dn[k];
            if (g+1 < G_CH-1) {
                #pragma unroll
                for (int k=0;k<4;k++){ int o=4*t+k; dn[k] = (o<W)? ws[WS_DELTA + (long)(g+1)*W + o] : 0.0f; }
            }
            const float4* c4 = (const float4*)&cbuf[pb][4*t];   // 16B aligned
            #pragma unroll
            for (int u=0;u<9;u++){
                float4 vv = c4[u];
                cc[4*u+0]=vv.x; cc[4*u+1]=vv.y; cc[4*u+2]=vv.z; cc[4*u+3]=vv.w;
            }
            #pragma unroll
            for (int k=0;k<4;k++) s[k]=dcur[k];
            #pragma unroll
            for (int j=0;j<=MCH;j++){
                float wj = wvr[j];
                #pragma unroll
                for (int k=0;k<4;k++) s[k] += wj*cc[32+k-j];
            }
            #pragma unroll
            for (int k=0;k<4;k++){
                int o = 4*t+k;
                if (o < W) {
                    cbuf[1-pb][o+32] = s[k];
                    ws[WS_CWINIT + (long)(g+1)*W + o] = s[k];
                    if (o >= W-32) cbuf[1-pb][o+32-W] = s[k];
                    if (o < 2)     cbuf[1-pb][o+32+W] = s[k];
                }
            }
        }
        __syncthreads();   // writes(1-pb) <-> next reads(1-pb)
        pb ^= 1;
    }
}

// ---------------- K3: KS pass C — true outputs + tail fade ------------------
__global__ __launch_bounds__(896) void k3_ksC(const float* __restrict__ fb,
                                              const float* __restrict__ ws,
                                              float* __restrict__ out) {
    __shared__ float sv[W];
    const int i = threadIdx.x;
    const int g = blockIdx.x;
    const float d2 = ws[WS_D2], fa = ws[WS_FA];
    float z = (i<W) ? ws[WS_CWINIT + (long)g*W + i] : 0.0f;
    const float* fbp = fb + (long)g*MCH*W + i;
    float* outp = out + (long)g*MCH*W + i;
    float cur = (i < W) ? fbp[0] : 0.0f;
    for (int j = 0; j < MCH; j++) {
        float nxt = 0.0f;
        if (j+1 < MCH && i < W) nxt = fbp[(long)(j+1)*W];
        float v = 0.0f;
        if (i < W) { v = z + tanhf(fa*cur); sv[i] = v; }
        __syncthreads();
        if (i < W) {
            float vp = sv[(i==0) ? (W-1) : (i-1)];
            z = d2 * (v + vp);
            outp[(long)j*W] = z;
        }
        __syncthreads();
        cur = nxt;
    }
    if (g == G_CH-1) {
        // remainder: one decay step without feedback, first 788 samples, fade tail
        if (i < W) sv[i] = z;
        __syncthreads();
        if (i < REMN) {
            float vp = sv[(i==0) ? (W-1) : (i-1)];
            float r = d2*(z + vp);
            int idx = REMSTART + i;
            if (idx >= NS-256) {
                float fj = (float)(idx - (NS-256));
                r *= (1.0f - fj*(1.0f/255.0f));
            }
            out[idx] = r;
        }
    }
}

// ---------------- K4: BR pass 1 — zero-y-state chunk offsets ----------------
__global__ __launch_bounds__(256) void k4_br1(const float* __restrict__ x,
                                              float* __restrict__ ws) {
    __shared__ float tile[256*33];
    const int tid = threadIdx.x;
    const int c = blockIdx.x*256 + tid;
    const long base = (long)blockIdx.x * (256*BRL);
    const float B0=ws[WS_B0],B1=ws[WS_B1],B2=ws[WS_B2],A1=ws[WS_A1],A2=ws[WS_A2];
    float x1, x2, y1=0.f, y2=0.f;
    {
        long g0 = (long)c * BRL;
        x1 = (c>0) ? x[g0-1] : 0.0f;
        x2 = (c>0) ? x[g0-2] : 0.0f;
    }
    for (int tt=0; tt<BRL/32; tt++) {
        const float4* src4 = (const float4*)(x + base + (long)tt*32);
        for (int q = tid; q < 256*8; q += 256) {
            int r = q >> 3, c4 = q & 7;
            float4 v = src4[(long)r*(BRL/4) + c4];
            tile[r*33 + c4*4 + 0] = v.x;
            tile[r*33 + c4*4 + 1] = v.y;
            tile[r*33 + c4*4 + 2] = v.z;
            tile[r*33 + c4*4 + 3] = v.w;
        }
        __syncthreads();
        #pragma unroll
        for (int j=0;j<32;j++){
            float xv = tile[tid*33 + j];
            float y = B0*xv + B1*x1 + B2*x2 - A1*y1 - A2*y2;
            x2=x1; x1=xv; y2=y1; y1=y;
        }
        __syncthreads();
    }
    ws[WS_BRD + 2*c]   = y1;
    ws[WS_BRD + 2*c+1] = y2;
    ws[WS_XT1 + c] = x1;
    ws[WS_XT2 + c] = x2;
}

// ---------------- K5: BR pass 2 — single-block state scan -------------------
__global__ __launch_bounds__(1024) void k5_scan(float* __restrict__ ws) {
    __shared__ float sa[1024], sb[1024];
    const int t = threadIdx.x;
    const float T00=ws[WS_T+0],T01=ws[WS_T+1],T10=ws[WS_T+2],T11=ws[WS_T+3];
    float m[10][4];
    #pragma unroll
    for (int k=0;k<10;k++){
        m[k][0]=ws[WS_M+4*k+0]; m[k][1]=ws[WS_M+4*k+1];
        m[k][2]=ws[WS_M+4*k+2]; m[k][3]=ws[WS_M+4*k+3];
    }
    float e1=0.f, e2=0.f;
    const long rb = (long)t * SCAN_R;
    for (int r=0;r<SCAN_R;r++){
        float d1  = ws[WS_BRD + 2*(rb+r)];
        float d2_ = ws[WS_BRD + 2*(rb+r)+1];
        float n1 = T00*e1 + T01*e2 + d1;
        float n2 = T10*e1 + T11*e2 + d2_;
        e1=n1; e2=n2;
    }
    float s1=e1, s2=e2;
    #pragma unroll
    for (int k=0;k<10;k++){
        sa[t]=s1; sb[t]=s2;
        __syncthreads();
        int off = 1<<k;
        float p1=0.f,p2=0.f;
        if (t >= off){ p1=sa[t-off]; p2=sb[t-off]; }
        __syncthreads();
        if (t >= off){
            s1 = s1 + m[k][0]*p1 + m[k][1]*p2;
            s2 = s2 + m[k][2]*p1 + m[k][3]*p2;
        }
    }
    sa[t]=s1; sb[t]=s2;
    __syncthreads();
    float y1 = (t>0)? sa[t-1] : 0.0f;
    float y2 = (t>0)? sb[t-1] : 0.0f;
    for (int r=0;r<SCAN_R;r++){
        long c = rb + r;
        ws[WS_BRS + 2*c]   = y1;
        ws[WS_BRS + 2*c+1] = y2;
        float d1  = ws[WS_BRD + 2*c];
        float d2_ = ws[WS_BRD + 2*c+1];
        float n1 = T00*y1 + T01*y2 + d1;
        float n2 = T10*y1 + T11*y2 + d2_;
        y1=n1; y2=n2;
    }
}

// ---------------- K6: BR pass 3 — true outputs + envelope, in-place ---------
__global__ __launch_bounds__(256) void k6_br2(float* __restrict__ x,
                                              const float* __restrict__ ws) {
    __shared__ float tile[256*33];
    const int tid = threadIdx.x;
    const int c = blockIdx.x*256 + tid;
    const long base = (long)blockIdx.x * (256*BRL);
    const float B0=ws[WS_B0],B1=ws[WS_B1],B2=ws[WS_B2],A1=ws[WS_A1],A2=ws[WS_A2];
    const float invA=ws[WS_INVA], invR=ws[WS_INVR];
    const float sa_ = ws[WS_SUS]*ws[WS_AMP];
    float x1 = (c>0)? ws[WS_XT1 + c-1] : 0.0f;
    float x2 = (c>0)? ws[WS_XT2 + c-1] : 0.0f;
    float y1 = ws[WS_BRS + 2*c];
    float y2 = ws[WS_BRS + 2*c+1];
    for (int tt=0; tt<BRL/32; tt++) {
        float4* dst4 = (float4*)(x + base + (long)tt*32);
        for (int q = tid; q < 256*8; q += 256) {
            int r = q >> 3, c4 = q & 7;
            float4 v = ((const float4*)dst4)[(long)r*(BRL/4) + c4];
            tile[r*33 + c4*4 + 0] = v.x;
            tile[r*33 + c4*4 + 1] = v.y;
            tile[r*33 + c4*4 + 2] = v.z;
            tile[r*33 + c4*4 + 3] = v.w;
        }
        __syncthreads();
        #pragma unroll
        for (int j=0;j<32;j++){
            float xv = tile[tid*33 + j];
            float y = B0*xv + B1*x1 + B2*x2 - A1*y1 - A2*y2;
            x2=x1; x1=xv; y2=y1; y1=y;
            int idx = c*BRL + tt*32 + j;
            float ea = fminf((float)idx * invA, 1.0f);
            float er = fminf((float)(NS-1-idx) * invR, 1.0f);
            tile[tid*33 + j] = y * (ea*er*sa_);
        }
        __syncthreads();
        for (int q = tid; q < 256*8; q += 256) {
            int r = q >> 3, c4 = q & 7;
            float4 v;
            v.x = tile[r*33 + c4*4 + 0];
            v.y = tile[r*33 + c4*4 + 1];
            v.z = tile[r*33 + c4*4 + 2];
            v.w = tile[r*33 + c4*4 + 3];
            dst4[(long)r*(BRL/4) + c4] = v;
        }
        __syncthreads();
    }
}

extern "C" void kernel_launch(void* const* d_in, const int* in_sizes, int n_in,
                              void* d_out, int out_size, void* d_ws, size_t ws_size,
                              hipStream_t stream) {
    const float* fb   = (const float*)d_in[0];
    const float* wt   = (const float*)d_in[1];
    const float* h    = (const float*)d_in[2];
    const float* envp = (const float*)d_in[3];
    const float* lp2c = (const float*)d_in[4];
    float* out = (float*)d_out;
    float* ws  = (float*)d_ws;

    hipLaunchKernelGGL(k0_setup, dim3(1),    dim3(64),   0, stream, wt, h, envp, lp2c, ws);
    hipLaunchKernelGGL(k1_ksA,   dim3(G_CH), dim3(896),  0, stream, fb, ws);
    hipLaunchKernelGGL(k2_ksB,   dim3(1),    dim3(256),  0, stream, ws);
    hipLaunchKernelGGL(k3_ksC,   dim3(G_CH), dim3(896),  0, stream, fb, ws, out);
    hipLaunchKernelGGL(k4_br1,   dim3(256),  dim3(256),  0, stream, out, ws);
    hipLaunchKernelGGL(k5_scan,  dim3(1),    dim3(1024), 0, stream, ws);
    hipLaunchKernelGGL(k6_br2,   dim3(256),  dim3(256),  0, stream, out, ws);
}

// Round 3
// 382.275 us; speedup vs baseline: 1.2854x; 1.2854x over previous
//
#include <hip/hip_runtime.h>
#include <math.h>

#define SRF 44100.0f
#define TWO_PI 6.283185307179586f
#define W 882
#define NHALF 441
#define NFREQ 442
#define MCH 30
#define G_CH 317
#define NS 8388608
#define REMSTART 8387820
#define REMN 788
#define BRL 128
#define BRC 65536
#define SCAN_R 64

// ---- ws float layout ----
#define WS_D2 0
#define WS_FA 1
#define WS_B0 2
#define WS_B1 3
#define WS_B2 4
#define WS_A1 5
#define WS_A2 6
#define WS_INVA 7
#define WS_INVR 8
#define WS_SUS 9
#define WS_AMP 10
#define WS_T 16
#define WS_M 24                        // 10 matrices x 4 -> 24..63
#define WS_CW0 64                      // 882 -> ends 946
#define WS_L1 948                      // 5 floats (b0,b1,b2,a1,a2 normalized)
#define WS_L2 956                      // 5 floats
#define WS_DELTA 1024                  // G_CH*W = 279594 -> ends 280618
#define WS_CH   1024                   // 317*884 = 280228 -> ends 281252 (overlaps DELTA: written by kB AFTER kA consumed DELTA)
#define WS_DH   281344                 // 317*884 = 280228 -> ends 561572
#define WS_CH0  561600                 // 884 -> ends 562484
// BR arrays reuse low region (KS finished before BR starts)
#define WS_BRD  1024                   // 2*BRC
#define WS_BRS  (WS_BRD + 2*BRC)       // 2*BRC
#define WS_XT1  (WS_BRS + 2*BRC)       // BRC
#define WS_XT2  (WS_XT1 + BRC)        // BRC -> ends 394240 (< WS_CH0, and DH dead by then)

// ---------------- K0: coefficients only (tiny) ------------------------------
__global__ void k0_setup(const float* __restrict__ h,
                         const float* __restrict__ envp,
                         const float* __restrict__ lp2c,
                         float* __restrict__ ws) {
    if (blockIdx.x != 0 || threadIdx.x != 0) return;
    float h0=h[0], h1=h[1], h2=h[2], h3=h[3], h4=h[4], h5=h[5], h6=h[6];
    float decay = fminf(fmaxf(h0 / 10.0f + 0.9f, 0.9f), 0.999f);
    ws[WS_D2] = decay * 0.5f;
    ws[WS_FA] = h3;

    // LP1 normalized coefs
    {
        float freq = fminf(fmaxf(h1 * (SRF/4.0f), 100.0f), SRF/2.0f - 1.0f);
        float q    = fminf(fmaxf(h2, 0.1f), 0.999f);
        float w0 = TWO_PI * freq / SRF;
        float sw = sinf(w0), cw = cosf(w0);
        float alpha = sw / (2.0f * q);
        float b0 = (1.0f - cw) * 0.5f, b1 = 1.0f - cw, b2 = b0;
        float a0 = 1.0f + alpha, a1 = -2.0f * cw, a2 = 1.0f - alpha;
        ws[WS_L1+0]=b0/a0; ws[WS_L1+1]=b1/a0; ws[WS_L1+2]=b2/a0;
        ws[WS_L1+3]=a1/a0; ws[WS_L1+4]=a2/a0;
    }
    // LP2 normalized coefs
    {
        float freq = 100.0f + lp2c[0]*8000.0f;
        float q = 0.707f;
        float w0 = TWO_PI * freq / SRF;
        float sw = sinf(w0), cw = cosf(w0);
        float alpha = sw / (2.0f * q);
        float b0 = (1.0f - cw) * 0.5f, b1 = 1.0f - cw, b2 = b0;
        float a0 = 1.0f + alpha, a1 = -2.0f * cw, a2 = 1.0f - alpha;
        ws[WS_L2+0]=b0/a0; ws[WS_L2+1]=b1/a0; ws[WS_L2+2]=b2/a0;
        ws[WS_L2+3]=a1/a0; ws[WS_L2+4]=a2/a0;
    }
    // bandreject coefs + scan matrices
    {
        float freq = fminf(fmaxf(h5*(SRF/4.0f), 100.0f), SRF/2.0f - 1.0f);
        float q = fminf(fmaxf(h6, 0.1f), 0.999f);
        float w0 = TWO_PI * freq / SRF;
        float sw = sinf(w0), cw = cosf(w0);
        float alpha = sw / (2.0f * q);
        float b0 = 1.0f, b1 = -2.0f*cw, b2 = 1.0f;
        float a0 = 1.0f + alpha, a1 = -2.0f*cw, a2 = 1.0f - alpha;
        ws[WS_B0]=b0/a0; ws[WS_B1]=b1/a0; ws[WS_B2]=b2/a0;
        float A1=a1/a0, A2=a2/a0;
        ws[WS_A1]=A1; ws[WS_A2]=A2;
        float t00=-A1, t01=-A2, t10=1.0f, t11=0.0f;
        for (int k=0;k<7;k++){
            float na=t00*t00+t01*t10, nb=t00*t01+t01*t11;
            float nc=t10*t00+t11*t10, nd=t10*t01+t11*t11;
            t00=na;t01=nb;t10=nc;t11=nd;
        }
        ws[WS_T+0]=t00; ws[WS_T+1]=t01; ws[WS_T+2]=t10; ws[WS_T+3]=t11;
        for (int k=0;k<6;k++){
            float na=t00*t00+t01*t10, nb=t00*t01+t01*t11;
            float nc=t10*t00+t11*t10, nd=t10*t01+t11*t11;
            t00=na;t01=nb;t10=nc;t11=nd;
        }
        for (int k=0;k<10;k++){
            ws[WS_M+4*k+0]=t00; ws[WS_M+4*k+1]=t01;
            ws[WS_M+4*k+2]=t10; ws[WS_M+4*k+3]=t11;
            float na=t00*t00+t01*t10, nb=t00*t01+t01*t11;
            float nc=t10*t00+t11*t10, nd=t10*t01+t11*t11;
            t00=na;t01=nb;t10=nc;t11=nd;
        }
    }
    // envelope
    {
        float nF = (float)NS;
        float attack  = 1.0f + envp[0]*0.1f*nF;
        float release = 1.0f + envp[2]*0.1f*nF;
        ws[WS_INVA] = 1.0f/attack;
        ws[WS_INVR] = 1.0f/release;
        ws[WS_SUS]  = fminf(fmaxf(envp[1], 0.0f), 1.0f);
        ws[WS_AMP]  = h4;
    }
}

// resolvent g_n of y_n = -a1 y_{n-1} - a2 y_{n-2}, g_0=1, g_1=-a1 (double internals)
__device__ float resolvent(float a1f, float a2f, int n) {
    double a1 = (double)a1f, a2 = (double)a2f;
    double disc = a1*a1 - 4.0*a2;
    double scale = a1*a1 + 4.0*fabs(a2) + 1e-30;
    if (disc > 1e-9*scale) {
        double sq = sqrt(disc);
        double p1 = 0.5*(-a1+sq), p2 = 0.5*(-a1-sq);
        int k = n+1;
        double t1 = pow(fabs(p1), (double)k); if (p1 < 0.0 && (k&1)) t1 = -t1;
        double t2 = pow(fabs(p2), (double)k); if (p2 < 0.0 && (k&1)) t2 = -t2;
        return (float)((t1 - t2)/sq);
    } else if (disc < -1e-9*scale) {
        double r = sqrt(a2);
        double ct = -a1/(2.0*r);
        ct = fmin(1.0, fmax(-1.0, ct));
        double th = acos(ct);
        double sth = sin(th);
        double rn = pow(r, (double)n);
        return (float)(rn * sin((double)(n+1)*th) / sth);
    } else {
        double p = -0.5*a1;
        double t = pow(fabs(p), (double)n); if (p < 0.0 && (n&1)) t = -t;
        return (float)((double)(n+1)*t);
    }
}

// ---------------- K0b: wavetable cascade filter via resolvent+conv ----------
__global__ __launch_bounds__(896) void k0b_wt(const float* __restrict__ wt,
                                              float* __restrict__ ws) {
    __shared__ float sx[W], sg[W], su[W], sy[W];
    const int i = threadIdx.x;
    const float b10=ws[WS_L1+0], b11=ws[WS_L1+1], b12=ws[WS_L1+2];
    const float a11=ws[WS_L1+3], a12=ws[WS_L1+4];
    const float b20=ws[WS_L2+0], b21=ws[WS_L2+1], b22=ws[WS_L2+2];
    const float a21=ws[WS_L2+3], a22=ws[WS_L2+4];
    if (i < W) { sx[i] = wt[i]; sg[i] = resolvent(a11, a12, i); }
    __syncthreads();
    if (i < W) {
        float acc = 0.0f;
        for (int k = 0; k <= i; k++) acc += sg[k]*sx[i-k];
        su[i] = acc;
    }
    __syncthreads();
    if (i < W) {
        float y = b10*su[i];
        if (i >= 1) y += b11*su[i-1];
        if (i >= 2) y += b12*su[i-2];
        sy[i] = y;
        sg[i] = resolvent(a21, a22, i);
    }
    __syncthreads();
    if (i < W) {
        float acc = 0.0f;
        for (int k = 0; k <= i; k++) acc += sg[k]*sy[i-k];
        su[i] = acc;
    }
    __syncthreads();
    if (i < W) {
        float y = b20*su[i];
        if (i >= 1) y += b21*su[i-1];
        if (i >= 2) y += b22*su[i-2];
        ws[WS_CW0 + i] = y;
    }
}

// ---------------- K1: KS pass A — zero-state chunk deltas -------------------
__global__ __launch_bounds__(896) void k1_ksA(const float* __restrict__ fb,
                                              float* __restrict__ ws) {
    __shared__ float sv[W];
    const int i = threadIdx.x;
    const int g = blockIdx.x;
    const float d2 = ws[WS_D2], fa = ws[WS_FA];
    float z = 0.0f;
    const float* fbp = fb + (long)g*MCH*W + i;
    float cur = (i < W) ? fbp[0] : 0.0f;
    for (int j = 0; j < MCH; j++) {
        float nxt = 0.0f;
        if (j+1 < MCH && i < W) nxt = fbp[(long)(j+1)*W];
        float v = 0.0f;
        if (i < W) { v = z + tanhf(fa*cur); sv[i] = v; }
        __syncthreads();
        if (i < W) {
            float vp = sv[(i==0) ? (W-1) : (i-1)];
            z = d2 * (v + vp);
        }
        __syncthreads();
        cur = nxt;
    }
    if (i < W) ws[WS_DELTA + g*W + i] = z;
}

// ---------------- KA: forward DFT (length-882, real input, 442 freqs) -------
// blocks 0..316: delta_g -> DH[g];  block 317: cw0 -> CH0
__global__ __launch_bounds__(896) void kA_dft(float* __restrict__ ws) {
    __shared__ float sx[W], cs[W], sn[W], se[NHALF], so[NHALF];
    const int i = threadIdx.x;
    const int g = blockIdx.x;
    const float* src = (g < G_CH) ? (ws + WS_DELTA + (long)g*W) : (ws + WS_CW0);
    float* dst = (g < G_CH) ? (ws + WS_DH + (long)g*(2*NFREQ)) : (ws + WS_CH0);
    if (i < W) {
        sx[i] = src[i];
        float ang = (float)i * (TWO_PI / (float)W);
        float s, c; __sincosf(ang, &s, &c);
        cs[i] = c; sn[i] = s;
    }
    __syncthreads();
    if (i < NHALF) { se[i] = sx[i] + sx[i+NHALF]; so[i] = sx[i] - sx[i+NHALF]; }
    __syncthreads();
    if (i < NFREQ) {
        const int f = i;
        const float* yb = (f & 1) ? so : se;
        float re = yb[0], im = 0.0f;
        int idx = 0;
        for (int k = 1; k < NHALF; k++) {
            idx += f; if (idx >= W) idx -= W;
            float y = yb[k];
            re += y * cs[idx];
            im -= y * sn[idx];
        }
        dst[2*f]   = re;
        dst[2*f+1] = im;
    }
}

// ---------------- KB: per-frequency scan over chunks ------------------------
__global__ __launch_bounds__(64) void kB_scan(float* __restrict__ ws) {
    const int f = blockIdx.x*64 + threadIdx.x;
    if (f >= NFREQ) return;
    const float d2 = ws[WS_D2];
    double phi = (double)f * (double)(TWO_PI) / (double)W;
    double m2 = 2.0 * (double)d2 * cos(0.5*phi);
    double mag = pow(m2, (double)MCH);            // m2 >= 0 for f in [0,441]
    double ang = -0.5 * (double)MCH * phi;        // -15*phi
    float mre = (float)(mag * cos(ang));
    float mim = (float)(mag * sin(ang));
    float cre = ws[WS_CH0 + 2*f];
    float cim = ws[WS_CH0 + 2*f+1];
    float* CH = ws + WS_CH;
    CH[2*f] = cre; CH[2*f+1] = cim;
    const float* DH = ws + WS_DH;
    for (int g = 1; g < G_CH; g++) {
        float dre = DH[(long)(g-1)*(2*NFREQ) + 2*f];
        float dim = DH[(long)(g-1)*(2*NFREQ) + 2*f+1];
        float nre = mre*cre - mim*cim + dre;
        float nim = mre*cim + mim*cre + dim;
        cre = nre; cim = nim;
        CH[(long)g*(2*NFREQ) + 2*f]   = cre;
        CH[(long)g*(2*NFREQ) + 2*f+1] = cim;
    }
}

// ---------------- K3: inline inverse DFT + true outputs + tail fade ---------
__global__ __launch_bounds__(896) void k3_ksC(const float* __restrict__ fb,
                                              const float* __restrict__ ws,
                                              float* __restrict__ out) {
    __shared__ float sv[W], cini[W], cs[W], sn[W], xr[NFREQ], xi[NFREQ];
    const int i = threadIdx.x;
    const int g = blockIdx.x;
    const float d2 = ws[WS_D2], fa = ws[WS_FA];
    if (i < W) {
        float ang = (float)i * (TWO_PI / (float)W);
        float s, c; __sincosf(ang, &s, &c);
        cs[i] = c; sn[i] = s;
    }
    if (i < NFREQ) {
        xr[i] = ws[WS_CH + (long)g*(2*NFREQ) + 2*i];
        xi[i] = ws[WS_CH + (long)g*(2*NFREQ) + 2*i+1];
    }
    __syncthreads();
    if (i < NHALF) {
        const int j = i;
        float E = 0.0f, O = 0.0f;
        int idx = 0;
        for (int f = 1; f < NHALF; f += 2) {
            idx += j; if (idx >= W) idx -= W;
            O += xr[f]*cs[idx] - xi[f]*sn[idx];
            idx += j; if (idx >= W) idx -= W;
            E += xr[f+1]*cs[idx] - xi[f+1]*sn[idx];
        }
        float base = xr[0];
        float x441 = xr[NHALF];
        float sg_ = (j & 1) ? -1.0f : 1.0f;
        cini[j]        = (base + sg_*x441 + 2.0f*(E+O)) * (1.0f/(float)W);
        cini[j+NHALF]  = (base - sg_*x441 + 2.0f*(E-O)) * (1.0f/(float)W);
    }
    __syncthreads();
    float z = (i < W) ? cini[i] : 0.0f;
    const float* fbp = fb + (long)g*MCH*W + i;
    float* outp = out + (long)g*MCH*W + i;
    float cur = (i < W) ? fbp[0] : 0.0f;
    for (int j = 0; j < MCH; j++) {
        float nxt = 0.0f;
        if (j+1 < MCH && i < W) nxt = fbp[(long)(j+1)*W];
        float v = 0.0f;
        if (i < W) { v = z + tanhf(fa*cur); sv[i] = v; }
        __syncthreads();
        if (i < W) {
            float vp = sv[(i==0) ? (W-1) : (i-1)];
            z = d2 * (v + vp);
            outp[(long)j*W] = z;
        }
        __syncthreads();
        cur = nxt;
    }
    if (g == G_CH-1) {
        if (i < W) sv[i] = z;
        __syncthreads();
        if (i < REMN) {
            float vp = sv[(i==0) ? (W-1) : (i-1)];
            float r = d2*(z + vp);
            int idx = REMSTART + i;
            if (idx >= NS-256) {
                float fj = (float)(idx - (NS-256));
                r *= (1.0f - fj*(1.0f/255.0f));
            }
            out[idx] = r;
        }
    }
}

// ---------------- K4: BR pass 1 — zero-y-state chunk offsets ----------------
__global__ __launch_bounds__(256) void k4_br1(const float* __restrict__ x,
                                              float* __restrict__ ws) {
    __shared__ float tile[256*33];
    const int tid = threadIdx.x;
    const int c = blockIdx.x*256 + tid;
    const long base = (long)blockIdx.x * (256*BRL);
    const float B0=ws[WS_B0],B1=ws[WS_B1],B2=ws[WS_B2],A1=ws[WS_A1],A2=ws[WS_A2];
    float x1, x2, y1=0.f, y2=0.f;
    {
        long g0 = (long)c * BRL;
        x1 = (c>0) ? x[g0-1] : 0.0f;
        x2 = (c>0) ? x[g0-2] : 0.0f;
    }
    for (int tt=0; tt<BRL/32; tt++) {
        const float4* src4 = (const float4*)(x + base + (long)tt*32);
        for (int q = tid; q < 256*8; q += 256) {
            int r = q >> 3, c4 = q & 7;
            float4 v = src4[(long)r*(BRL/4) + c4];
            tile[r*33 + c4*4 + 0] = v.x;
            tile[r*33 + c4*4 + 1] = v.y;
            tile[r*33 + c4*4 + 2] = v.z;
            tile[r*33 + c4*4 + 3] = v.w;
        }
        __syncthreads();
        #pragma unroll
        for (int j=0;j<32;j++){
            float xv = tile[tid*33 + j];
            float y = B0*xv + B1*x1 + B2*x2 - A1*y1 - A2*y2;
            x2=x1; x1=xv; y2=y1; y1=y;
        }
        __syncthreads();
    }
    ws[WS_BRD + 2*c]   = y1;
    ws[WS_BRD + 2*c+1] = y2;
    ws[WS_XT1 + c] = x1;
    ws[WS_XT2 + c] = x2;
}

// ---------------- K5: BR pass 2 — single-block state scan -------------------
__global__ __launch_bounds__(1024) void k5_scan(float* __restrict__ ws) {
    __shared__ float sa[1024], sb[1024];
    const int t = threadIdx.x;
    const float T00=ws[WS_T+0],T01=ws[WS_T+1],T10=ws[WS_T+2],T11=ws[WS_T+3];
    float m[10][4];
    #pragma unroll
    for (int k=0;k<10;k++){
        m[k][0]=ws[WS_M+4*k+0]; m[k][1]=ws[WS_M+4*k+1];
        m[k][2]=ws[WS_M+4*k+2]; m[k][3]=ws[WS_M+4*k+3];
    }
    float e1=0.f, e2=0.f;
    const long rb = (long)t * SCAN_R;
    for (int r=0;r<SCAN_R;r++){
        float d1  = ws[WS_BRD + 2*(rb+r)];
        float d2_ = ws[WS_BRD + 2*(rb+r)+1];
        float n1 = T00*e1 + T01*e2 + d1;
        float n2 = T10*e1 + T11*e2 + d2_;
        e1=n1; e2=n2;
    }
    float s1=e1, s2=e2;
    #pragma unroll
    for (int k=0;k<10;k++){
        sa[t]=s1; sb[t]=s2;
        __syncthreads();
        int off = 1<<k;
        float p1=0.f,p2=0.f;
        if (t >= off){ p1=sa[t-off]; p2=sb[t-off]; }
        __syncthreads();
        if (t >= off){
            s1 = s1 + m[k][0]*p1 + m[k][1]*p2;
            s2 = s2 + m[k][2]*p1 + m[k][3]*p2;
        }
    }
    sa[t]=s1; sb[t]=s2;
    __syncthreads();
    float y1 = (t>0)? sa[t-1] : 0.0f;
    float y2 = (t>0)? sb[t-1] : 0.0f;
    for (int r=0;r<SCAN_R;r++){
        long c = rb + r;
        ws[WS_BRS + 2*c]   = y1;
        ws[WS_BRS + 2*c+1] = y2;
        float d1  = ws[WS_BRD + 2*c];
        float d2_ = ws[WS_BRD + 2*c+1];
        float n1 = T00*y1 + T01*y2 + d1;
        float n2 = T10*y1 + T11*y2 + d2_;
        y1=n1; y2=n2;
    }
}

// ---------------- K6: BR pass 3 — true outputs + envelope, in-place ---------
__global__ __launch_bounds__(256) void k6_br2(float* __restrict__ x,
                                              const float* __restrict__ ws) {
    __shared__ float tile[256*33];
    const int tid = threadIdx.x;
    const int c = blockIdx.x*256 + tid;
    const long base = (long)blockIdx.x * (256*BRL);
    const float B0=ws[WS_B0],B1=ws[WS_B1],B2=ws[WS_B2],A1=ws[WS_A1],A2=ws[WS_A2];
    const float invA=ws[WS_INVA], invR=ws[WS_INVR];
    const float sa_ = ws[WS_SUS]*ws[WS_AMP];
    float x1 = (c>0)? ws[WS_XT1 + c-1] : 0.0f;
    float x2 = (c>0)? ws[WS_XT2 + c-1] : 0.0f;
    float y1 = ws[WS_BRS + 2*c];
    float y2 = ws[WS_BRS + 2*c+1];
    for (int tt=0; tt<BRL/32; tt++) {
        float4* dst4 = (float4*)(x + base + (long)tt*32);
        for (int q = tid; q < 256*8; q += 256) {
            int r = q >> 3, c4 = q & 7;
            float4 v = ((const float4*)dst4)[(long)r*(BRL/4) + c4];
            tile[r*33 + c4*4 + 0] = v.x;
            tile[r*33 + c4*4 + 1] = v.y;
            tile[r*33 + c4*4 + 2] = v.z;
            tile[r*33 + c4*4 + 3] = v.w;
        }
        __syncthreads();
        #pragma unroll
        for (int j=0;j<32;j++){
            float xv = tile[tid*33 + j];
            float y = B0*xv + B1*x1 + B2*x2 - A1*y1 - A2*y2;
            x2=x1; x1=xv; y2=y1; y1=y;
            int idx = c*BRL + tt*32 + j;
            float ea = fminf((float)idx * invA, 1.0f);
            float er = fminf((float)(NS-1-idx) * invR, 1.0f);
            tile[tid*33 + j] = y * (ea*er*sa_);
        }
        __syncthreads();
        for (int q = tid; q < 256*8; q += 256) {
            int r = q >> 3, c4 = q & 7;
            float4 v;
            v.x = tile[r*33 + c4*4 + 0];
            v.y = tile[r*33 + c4*4 + 1];
            v.z = tile[r*33 + c4*4 + 2];
            v.w = tile[r*33 + c4*4 + 3];
            dst4[(long)r*(BRL/4) + c4] = v;
        }
        __syncthreads();
    }
}

extern "C" void kernel_launch(void* const* d_in, const int* in_sizes, int n_in,
                              void* d_out, int out_size, void* d_ws, size_t ws_size,
                              hipStream_t stream) {
    const float* fb   = (const float*)d_in[0];
    const float* wt   = (const float*)d_in[1];
    const float* h    = (const float*)d_in[2];
    const float* envp = (const float*)d_in[3];
    const float* lp2c = (const float*)d_in[4];
    float* out = (float*)d_out;
    float* ws  = (float*)d_ws;

    hipLaunchKernelGGL(k0_setup, dim3(1),      dim3(64),   0, stream, h, envp, lp2c, ws);
    hipLaunchKernelGGL(k0b_wt,   dim3(1),      dim3(896),  0, stream, wt, ws);
    hipLaunchKernelGGL(k1_ksA,   dim3(G_CH),   dim3(896),  0, stream, fb, ws);
    hipLaunchKernelGGL(kA_dft,   dim3(G_CH+1), dim3(896),  0, stream, ws);
    hipLaunchKernelGGL(kB_scan,  dim3(7),      dim3(64),   0, stream, ws);
    hipLaunchKernelGGL(k3_ksC,   dim3(G_CH),   dim3(896),  0, stream, fb, ws, out);
    hipLaunchKernelGGL(k4_br1,   dim3(256),    dim3(256),  0, stream, out, ws);
    hipLaunchKernelGGL(k5_scan,  dim3(1),      dim3(1024), 0, stream, ws);
    hipLaunchKernelGGL(k6_br2,   dim3(256),    dim3(256),  0, stream, out, ws);
}

// Round 5
// 332.814 us; speedup vs baseline: 1.4764x; 1.1486x over previous
//
#include <hip/hip_runtime.h>
#include <math.h>

#define SRF 44100.0f
#define TWO_PI 6.283185307179586f
#define W 882
#define NHALF 441
#define NFREQ 442
#define MCH 30
#define G_CH 317
#define NS 8388608
#define REMSTART 8387820
#define REMN 788
#define BRL 128
#define BRC 65536
#define SCAN_R 64

// ---- ws float layout ----
#define WS_D2 0
#define WS_FA 1
#define WS_B0 2
#define WS_B1 3
#define WS_B2 4
#define WS_A1 5
#define WS_A2 6
#define WS_INVA 7
#define WS_INVR 8
#define WS_SUS 9
#define WS_AMP 10
#define WS_T 16
#define WS_M 24                        // 10 matrices x 4 -> 24..63
#define WS_CW0 64                      // 882 -> ends 946
#define WS_L1 948                      // 5 floats
#define WS_L2 956                      // 5 floats
#define WS_CH   1024                   // 317*884 = 280228 -> ends 281252
#define WS_DH   281344                 // 317*884 -> ends 561572
#define WS_CH0  561600                 // 884 -> ends 562484
// BR arrays reuse low region (KS finished before BR starts); DH dead after kB
#define WS_BRD  1024                   // 2*BRC
#define WS_BRS  (WS_BRD + 2*BRC)       // 2*BRC
#define WS_XT1  (WS_BRS + 2*BRC)       // BRC
#define WS_XT2  (WS_XT1 + BRC)         // BRC -> ends 394240

// ---------------- K0: coefficients only (tiny) ------------------------------
__global__ void k0_setup(const float* __restrict__ h,
                         const float* __restrict__ envp,
                         const float* __restrict__ lp2c,
                         float* __restrict__ ws) {
    if (blockIdx.x != 0 || threadIdx.x != 0) return;
    float h0=h[0], h1=h[1], h2=h[2], h3=h[3], h4=h[4], h5=h[5], h6=h[6];
    float decay = fminf(fmaxf(h0 / 10.0f + 0.9f, 0.9f), 0.999f);
    ws[WS_D2] = decay * 0.5f;
    ws[WS_FA] = h3;
    {
        float freq = fminf(fmaxf(h1 * (SRF/4.0f), 100.0f), SRF/2.0f - 1.0f);
        float q    = fminf(fmaxf(h2, 0.1f), 0.999f);
        float w0 = TWO_PI * freq / SRF;
        float sw = sinf(w0), cw = cosf(w0);
        float alpha = sw / (2.0f * q);
        float b0 = (1.0f - cw) * 0.5f, b1 = 1.0f - cw, b2 = b0;
        float a0 = 1.0f + alpha, a1 = -2.0f * cw, a2 = 1.0f - alpha;
        ws[WS_L1+0]=b0/a0; ws[WS_L1+1]=b1/a0; ws[WS_L1+2]=b2/a0;
        ws[WS_L1+3]=a1/a0; ws[WS_L1+4]=a2/a0;
    }
    {
        float freq = 100.0f + lp2c[0]*8000.0f;
        float q = 0.707f;
        float w0 = TWO_PI * freq / SRF;
        float sw = sinf(w0), cw = cosf(w0);
        float alpha = sw / (2.0f * q);
        float b0 = (1.0f - cw) * 0.5f, b1 = 1.0f - cw, b2 = b0;
        float a0 = 1.0f + alpha, a1 = -2.0f * cw, a2 = 1.0f - alpha;
        ws[WS_L2+0]=b0/a0; ws[WS_L2+1]=b1/a0; ws[WS_L2+2]=b2/a0;
        ws[WS_L2+3]=a1/a0; ws[WS_L2+4]=a2/a0;
    }
    {
        float freq = fminf(fmaxf(h5*(SRF/4.0f), 100.0f), SRF/2.0f - 1.0f);
        float q = fminf(fmaxf(h6, 0.1f), 0.999f);
        float w0 = TWO_PI * freq / SRF;
        float sw = sinf(w0), cw = cosf(w0);
        float alpha = sw / (2.0f * q);
        float b0 = 1.0f, b1 = -2.0f*cw, b2 = 1.0f;
        float a0 = 1.0f + alpha, a1 = -2.0f*cw, a2 = 1.0f - alpha;
        ws[WS_B0]=b0/a0; ws[WS_B1]=b1/a0; ws[WS_B2]=b2/a0;
        float A1=a1/a0, A2=a2/a0;
        ws[WS_A1]=A1; ws[WS_A2]=A2;
        float t00=-A1, t01=-A2, t10=1.0f, t11=0.0f;
        for (int k=0;k<7;k++){
            float na=t00*t00+t01*t10, nb=t00*t01+t01*t11;
            float nc=t10*t00+t11*t10, nd=t10*t01+t11*t11;
            t00=na;t01=nb;t10=nc;t11=nd;
        }
        ws[WS_T+0]=t00; ws[WS_T+1]=t01; ws[WS_T+2]=t10; ws[WS_T+3]=t11;
        for (int k=0;k<6;k++){
            float na=t00*t00+t01*t10, nb=t00*t01+t01*t11;
            float nc=t10*t00+t11*t10, nd=t10*t01+t11*t11;
            t00=na;t01=nb;t10=nc;t11=nd;
        }
        for (int k=0;k<10;k++){
            ws[WS_M+4*k+0]=t00; ws[WS_M+4*k+1]=t01;
            ws[WS_M+4*k+2]=t10; ws[WS_M+4*k+3]=t11;
            float na=t00*t00+t01*t10, nb=t00*t01+t01*t11;
            float nc=t10*t00+t11*t10, nd=t10*t01+t11*t11;
            t00=na;t01=nb;t10=nc;t11=nd;
        }
    }
    {
        float nF = (float)NS;
        float attack  = 1.0f + envp[0]*0.1f*nF;
        float release = 1.0f + envp[2]*0.1f*nF;
        ws[WS_INVA] = 1.0f/attack;
        ws[WS_INVR] = 1.0f/release;
        ws[WS_SUS]  = fminf(fmaxf(envp[1], 0.0f), 1.0f);
        ws[WS_AMP]  = h4;
    }
}

// resolvent g_n of y_n = -a1 y_{n-1} - a2 y_{n-2}, g_0=1, g_1=-a1
__device__ float resolvent(float a1f, float a2f, int n) {
    double a1 = (double)a1f, a2 = (double)a2f;
    double disc = a1*a1 - 4.0*a2;
    double scale = a1*a1 + 4.0*fabs(a2) + 1e-30;
    if (disc > 1e-9*scale) {
        double sq = sqrt(disc);
        double p1 = 0.5*(-a1+sq), p2 = 0.5*(-a1-sq);
        int k = n+1;
        double t1 = pow(fabs(p1), (double)k); if (p1 < 0.0 && (k&1)) t1 = -t1;
        double t2 = pow(fabs(p2), (double)k); if (p2 < 0.0 && (k&1)) t2 = -t2;
        return (float)((t1 - t2)/sq);
    } else if (disc < -1e-9*scale) {
        double r = sqrt(a2);
        double ct = -a1/(2.0*r);
        ct = fmin(1.0, fmax(-1.0, ct));
        double th = acos(ct);
        double sth = sin(th);
        double rn = pow(r, (double)n);
        return (float)(rn * sin((double)(n+1)*th) / sth);
    } else {
        double p = -0.5*a1;
        double t = pow(fabs(p), (double)n); if (p < 0.0 && (n&1)) t = -t;
        return (float)((double)(n+1)*t);
    }
}

// ---------------- K0b: wavetable cascade filter + forward DFT -> CH0 --------
__global__ __launch_bounds__(896) void k0b_wt(const float* __restrict__ wt,
                                              float* __restrict__ ws) {
    __shared__ float sx[W], sg[W], su[W], sy[W];
    const int i = threadIdx.x;
    const float b10=ws[WS_L1+0], b11=ws[WS_L1+1], b12=ws[WS_L1+2];
    const float a11=ws[WS_L1+3], a12=ws[WS_L1+4];
    const float b20=ws[WS_L2+0], b21=ws[WS_L2+1], b22=ws[WS_L2+2];
    const float a21=ws[WS_L2+3], a22=ws[WS_L2+4];
    if (i < W) { sx[i] = wt[i]; sg[i] = resolvent(a11, a12, i); }
    __syncthreads();
    if (i < W) {
        float acc = 0.0f;
        for (int k = 0; k <= i; k++) acc += sg[k]*sx[i-k];
        su[i] = acc;
    }
    __syncthreads();
    if (i < W) {
        float y = b10*su[i];
        if (i >= 1) y += b11*su[i-1];
        if (i >= 2) y += b12*su[i-2];
        sy[i] = y;
        sg[i] = resolvent(a21, a22, i);
    }
    __syncthreads();
    if (i < W) {
        float acc = 0.0f;
        for (int k = 0; k <= i; k++) acc += sg[k]*sy[i-k];
        su[i] = acc;
    }
    __syncthreads();
    if (i < W) {
        float y = b20*su[i];
        if (i >= 1) y += b21*su[i-1];
        if (i >= 2) y += b22*su[i-2];
        ws[WS_CW0 + i] = y;
        sy[i] = y;
    }
    __syncthreads();
    // fold: su = even part, sg = odd part
    if (i < NHALF) { su[i] = sy[i] + sy[i+NHALF]; sg[i] = sy[i] - sy[i+NHALF]; }
    __syncthreads();
    if (i < NFREQ) {
        const int f = i;
        const float* yb = (f & 1) ? sg : su;
        float ang = (float)f * (TWO_PI / (float)W);
        float S, C; __sincosf(ang, &S, &C);
        float cr = 1.0f, ci = 0.0f;      // e^{-i phi f k} at k=0
        float re = 0.0f, im = 0.0f;
        for (int k = 0; k < NHALF; k++) {
            float y = yb[k];
            re = fmaf(y, cr, re);
            im = fmaf(y, ci, im);
            float t = cr;
            cr = fmaf(t, C,  ci*S);      // *(C - iS)
            ci = fmaf(ci, C, -t*S);
        }
        ws[WS_CH0 + 2*f]   = re;
        ws[WS_CH0 + 2*f+1] = im;
    }
}

// ---------------- K1: KS pass A — zero-state deltas + fused forward DFT -----
__global__ __launch_bounds__(896) void k1_ksA(const float* __restrict__ fb,
                                              float* __restrict__ ws) {
    __shared__ float sv[W], se[NHALF], so[NHALF];
    __shared__ float sbb[2][16];
    const int i = threadIdx.x;
    const int lane = i & 63, wv = i >> 6;
    const int g = blockIdx.x;
    const float d2 = ws[WS_D2], fa = ws[WS_FA];
    const bool act = (i < W);
    const float* fbp = fb + (long)g*MCH*W + i;
    float fbr[MCH];
    #pragma unroll
    for (int j = 0; j < MCH; j++) fbr[j] = act ? fbp[(long)j*W] : 0.0f;
    float z = 0.0f;
    #pragma unroll
    for (int j = 0; j < MCH; j++) {
        float v = z + tanhf(fa*fbr[j]);
        if (lane == 63 && wv < 13) sbb[j&1][wv+1] = v;
        if (i == W-1)              sbb[j&1][0]    = v;
        float vs = __shfl_up(v, 1);
        __syncthreads();
        float vp = (lane == 0) ? sbb[j&1][wv] : vs;
        z = d2*(v + vp);
    }
    if (act) sv[i] = z;
    __syncthreads();
    if (i < NHALF) { se[i] = sv[i] + sv[i+NHALF]; so[i] = sv[i] - sv[i+NHALF]; }
    __syncthreads();
    if (i < NFREQ) {
        const int f = i;
        const float* yb = (f & 1) ? so : se;
        float ang = (float)f * (TWO_PI / (float)W);
        float S, C; __sincosf(ang, &S, &C);
        float cr = 1.0f, ci = 0.0f;
        float re = 0.0f, im = 0.0f;
        for (int k = 0; k < NHALF; k++) {
            float y = yb[k];
            re = fmaf(y, cr, re);
            im = fmaf(y, ci, im);
            float t = cr;
            cr = fmaf(t, C,  ci*S);
            ci = fmaf(ci, C, -t*S);
        }
        float* dst = ws + WS_DH + (long)g*(2*NFREQ);
        dst[2*f]   = re;
        dst[2*f+1] = im;
    }
}

// ---------------- KB: per-frequency scan over chunks ------------------------
__global__ __launch_bounds__(64) void kB_scan(float* __restrict__ ws) {
    const int f = blockIdx.x*64 + threadIdx.x;
    if (f >= NFREQ) return;
    const float d2 = ws[WS_D2];
    double phi = (double)f * (double)(TWO_PI) / (double)W;
    double m2 = 2.0 * (double)d2 * cos(0.5*phi);
    double mag = pow(m2, (double)MCH);
    double ang = -0.5 * (double)MCH * phi;
    float mre = (float)(mag * cos(ang));
    float mim = (float)(mag * sin(ang));
    float cre = ws[WS_CH0 + 2*f];
    float cim = ws[WS_CH0 + 2*f+1];
    float* CH = ws + WS_CH;
    CH[2*f] = cre; CH[2*f+1] = cim;
    const float* DH = ws + WS_DH;
    for (int g = 1; g < G_CH; g++) {
        float dre = DH[(long)(g-1)*(2*NFREQ) + 2*f];
        float dim = DH[(long)(g-1)*(2*NFREQ) + 2*f+1];
        float nre = mre*cre - mim*cim + dre;
        float nim = mre*cim + mim*cre + dim;
        cre = nre; cim = nim;
        CH[(long)g*(2*NFREQ) + 2*f]   = cre;
        CH[(long)g*(2*NFREQ) + 2*f+1] = cim;
    }
}

// ---------------- K3: rotation-IDFT + true outputs + tail fade --------------
__global__ __launch_bounds__(896) void k3_ksC(const float* __restrict__ fb,
                                              const float* __restrict__ ws,
                                              float* __restrict__ out) {
    __shared__ float chs[2*NFREQ];
    __shared__ float sbb[2][16];
    const int i = threadIdx.x;
    const int lane = i & 63, wv = i >> 6;
    const int g = blockIdx.x;
    const float d2 = ws[WS_D2], fa = ws[WS_FA];
    const bool act = (i < W);
    const float* fbp = fb + (long)g*MCH*W + i;
    float* outp = out + (long)g*MCH*W + i;
    float fbr[MCH];
    #pragma unroll
    for (int j = 0; j < MCH; j++) fbr[j] = act ? fbp[(long)j*W] : 0.0f;
    if (i < 2*NFREQ) chs[i] = ws[WS_CH + (long)g*(2*NFREQ) + i];
    __syncthreads();
    // inverse DFT by rotation: z = (1/W)(X0 + (-1)^i X441 + 2*sum Re(X_f e^{+i phi i f}))
    float z = 0.0f;
    if (act) {
        float ang = (float)i * (TWO_PI / (float)W);
        float S, C; __sincosf(ang, &S, &C);
        float cr = C, ci = S;           // value at f=1
        float acc = 0.0f;
        for (int f = 1; f <= 440; f++) {
            float xr = chs[2*f], xi = chs[2*f+1];
            acc += xr*cr - xi*ci;
            float t = cr;
            cr = fmaf(t, C, -ci*S);     // *(C + iS)
            ci = fmaf(ci, C,  t*S);
        }
        float sgn = (i & 1) ? -1.0f : 1.0f;
        z = (chs[0] + sgn*chs[2*NHALF] + 2.0f*acc) * (1.0f/(float)W);
    }
    #pragma unroll
    for (int j = 0; j < MCH; j++) {
        float v = z + tanhf(fa*fbr[j]);
        if (lane == 63 && wv < 13) sbb[j&1][wv+1] = v;
        if (i == W-1)              sbb[j&1][0]    = v;
        float vs = __shfl_up(v, 1);
        __syncthreads();
        float vp = (lane == 0) ? sbb[j&1][wv] : vs;
        z = d2*(v + vp);
        if (act) outp[(long)j*W] = z;
    }
    if (g == G_CH-1) {
        float v = z;
        if (lane == 63 && wv < 13) sbb[0][wv+1] = v;
        if (i == W-1)              sbb[0][0]    = v;
        float vs = __shfl_up(v, 1);
        __syncthreads();
        float vp = (lane == 0) ? sbb[0][wv] : vs;
        float r = d2*(v + vp);
        if (i < REMN) {
            int idx = REMSTART + i;
            if (idx >= NS-256) {
                float fj = (float)(idx - (NS-256));
                r *= (1.0f - fj*(1.0f/255.0f));
            }
            out[idx] = r;
        }
    }
}

// ---------------- K4: BR pass 1 — zero-y-state chunk offsets ----------------
__global__ __launch_bounds__(256) void k4_br1(const float* __restrict__ x,
                                              float* __restrict__ ws) {
    __shared__ float tile[256*33];
    const int tid = threadIdx.x;
    const int c = blockIdx.x*256 + tid;
    const long base = (long)blockIdx.x * (256*BRL);
    const float B0=ws[WS_B0],B1=ws[WS_B1],B2=ws[WS_B2],A1=ws[WS_A1],A2=ws[WS_A2];
    float x1, x2, y1=0.f, y2=0.f;
    {
        long g0 = (long)c * BRL;
        x1 = (c>0) ? x[g0-1] : 0.0f;
        x2 = (c>0) ? x[g0-2] : 0.0f;
    }
    for (int tt=0; tt<BRL/32; tt++) {
        const float4* src4 = (const float4*)(x + base + (long)tt*32);
        for (int q = tid; q < 256*8; q += 256) {
            int r = q >> 3, c4 = q & 7;
            float4 v = src4[(long)r*(BRL/4) + c4];
            tile[r*33 + c4*4 + 0] = v.x;
            tile[r*33 + c4*4 + 1] = v.y;
            tile[r*33 + c4*4 + 2] = v.z;
            tile[r*33 + c4*4 + 3] = v.w;
        }
        __syncthreads();
        #pragma unroll
        for (int j=0;j<32;j++){
            float xv = tile[tid*33 + j];
            float y = B0*xv + B1*x1 + B2*x2 - A1*y1 - A2*y2;
            x2=x1; x1=xv; y2=y1; y1=y;
        }
        __syncthreads();
    }
    ws[WS_BRD + 2*c]   = y1;
    ws[WS_BRD + 2*c+1] = y2;
    ws[WS_XT1 + c] = x1;
    ws[WS_XT2 + c] = x2;
}

// ---------------- K5: BR pass 2 — single-block state scan -------------------
__global__ __launch_bounds__(1024) void k5_scan(float* __restrict__ ws) {
    __shared__ float sa[1024], sb[1024];
    const int t = threadIdx.x;
    const float T00=ws[WS_T+0],T01=ws[WS_T+1],T10=ws[WS_T+2],T11=ws[WS_T+3];
    float m[10][4];
    #pragma unroll
    for (int k=0;k<10;k++){
        m[k][0]=ws[WS_M+4*k+0]; m[k][1]=ws[WS_M+4*k+1];
        m[k][2]=ws[WS_M+4*k+2]; m[k][3]=ws[WS_M+4*k+3];
    }
    float e1=0.f, e2=0.f;
    const long rb = (long)t * SCAN_R;
    for (int r=0;r<SCAN_R;r++){
        float d1  = ws[WS_BRD + 2*(rb+r)];
        float d2_ = ws[WS_BRD + 2*(rb+r)+1];
        float n1 = T00*e1 + T01*e2 + d1;
        float n2 = T10*e1 + T11*e2 + d2_;
        e1=n1; e2=n2;
    }
    float s1=e1, s2=e2;
    #pragma unroll
    for (int k=0;k<10;k++){
        sa[t]=s1; sb[t]=s2;
        __syncthreads();
        int off = 1<<k;
        float p1=0.f,p2=0.f;
        if (t >= off){ p1=sa[t-off]; p2=sb[t-off]; }
        __syncthreads();
        if (t >= off){
            s1 = s1 + m[k][0]*p1 + m[k][1]*p2;
            s2 = s2 + m[k][2]*p1 + m[k][3]*p2;
        }
    }
    sa[t]=s1; sb[t]=s2;
    __syncthreads();
    float y1 = (t>0)? sa[t-1] : 0.0f;
    float y2 = (t>0)? sb[t-1] : 0.0f;
    for (int r=0;r<SCAN_R;r++){
        long c = rb + r;
        ws[WS_BRS + 2*c]   = y1;
        ws[WS_BRS + 2*c+1] = y2;
        float d1  = ws[WS_BRD + 2*c];
        float d2_ = ws[WS_BRD + 2*c+1];
        float n1 = T00*y1 + T01*y2 + d1;
        float n2 = T10*y1 + T11*y2 + d2_;
        y1=n1; y2=n2;
    }
}

// ---------------- K6: BR pass 3 — true outputs + envelope, in-place ---------
__global__ __launch_bounds__(256) void k6_br2(float* __restrict__ x,
                                              const float* __restrict__ ws) {
    __shared__ float tile[256*33];
    const int tid = threadIdx.x;
    const int c = blockIdx.x*256 + tid;
    const long base = (long)blockIdx.x * (256*BRL);
    const float B0=ws[WS_B0],B1=ws[WS_B1],B2=ws[WS_B2],A1=ws[WS_A1],A2=ws[WS_A2];
    const float invA=ws[WS_INVA], invR=ws[WS_INVR];
    const float sa_ = ws[WS_SUS]*ws[WS_AMP];
    float x1 = (c>0)? ws[WS_XT1 + c-1] : 0.0f;
    float x2 = (c>0)? ws[WS_XT2 + c-1] : 0.0f;
    float y1 = ws[WS_BRS + 2*c];
    float y2 = ws[WS_BRS + 2*c+1];
    for (int tt=0; tt<BRL/32; tt++) {
        float4* dst4 = (float4*)(x + base + (long)tt*32);
        for (int q = tid; q < 256*8; q += 256) {
            int r = q >> 3, c4 = q & 7;
            float4 v = ((const float4*)dst4)[(long)r*(BRL/4) + c4];
            tile[r*33 + c4*4 + 0] = v.x;
            tile[r*33 + c4*4 + 1] = v.y;
            tile[r*33 + c4*4 + 2] = v.z;
            tile[r*33 + c4*4 + 3] = v.w;
        }
        __syncthreads();
        #pragma unroll
        for (int j=0;j<32;j++){
            float xv = tile[tid*33 + j];
            float y = B0*xv + B1*x1 + B2*x2 - A1*y1 - A2*y2;
            x2=x1; x1=xv; y2=y1; y1=y;
            int idx = c*BRL + tt*32 + j;
            float ea = fminf((float)idx * invA, 1.0f);
            float er = fminf((float)(NS-1-idx) * invR, 1.0f);
            tile[tid*33 + j] = y * (ea*er*sa_);
        }
        __syncthreads();
        for (int q = tid; q < 256*8; q += 256) {
            int r = q >> 3, c4 = q & 7;
            float4 v;
            v.x = tile[r*33 + c4*4 + 0];
            v.y = tile[r*33 + c4*4 + 1];
            v.z = tile[r*33 + c4*4 + 2];
            v.w = tile[r*33 + c4*4 + 3];
            dst4[(long)r*(BRL/4) + c4] = v;
        }
        __syncthreads();
    }
}

extern "C" void kernel_launch(void* const* d_in, const int* in_sizes, int n_in,
                              void* d_out, int out_size, void* d_ws, size_t ws_size,
                              hipStream_t stream) {
    const float* fb   = (const float*)d_in[0];
    const float* wt   = (const float*)d_in[1];
    const float* h    = (const float*)d_in[2];
    const float* envp = (const float*)d_in[3];
    const float* lp2c = (const float*)d_in[4];
    float* out = (float*)d_out;
    float* ws  = (float*)d_ws;

    hipLaunchKernelGGL(k0_setup, dim3(1),    dim3(64),   0, stream, h, envp, lp2c, ws);
    hipLaunchKernelGGL(k0b_wt,   dim3(1),    dim3(896),  0, stream, wt, ws);
    hipLaunchKernelGGL(k1_ksA,   dim3(G_CH), dim3(896),  0, stream, fb, ws);
    hipLaunchKernelGGL(kB_scan,  dim3(7),    dim3(64),   0, stream, ws);
    hipLaunchKernelGGL(k3_ksC,   dim3(G_CH), dim3(896),  0, stream, fb, ws, out);
    hipLaunchKernelGGL(k4_br1,   dim3(256),  dim3(256),  0, stream, out, ws);
    hipLaunchKernelGGL(k5_scan,  dim3(1),    dim3(1024), 0, stream, ws);
    hipLaunchKernelGGL(k6_br2,   dim3(256),  dim3(256),  0, stream, out, ws);
}

// Round 6
// 323.374 us; speedup vs baseline: 1.5195x; 1.0292x over previous
//
#include <hip/hip_runtime.h>
#include <math.h>

#define SRF 44100.0f
#define TWO_PI 6.283185307179586f
#define W 882
#define NHALF 441
#define NFREQ 442
#define MCH 30
#define G_CH 317
#define NS 8388608
#define REMSTART 8387820
#define REMN 788
#define BRL 128
#define BRC 65536
#define SCAN_R 64

// ---- ws float layout ----
#define WS_D2 0
#define WS_FA 1
#define WS_B0 2
#define WS_B1 3
#define WS_B2 4
#define WS_A1 5
#define WS_A2 6
#define WS_INVA 7
#define WS_INVR 8
#define WS_SUS 9
#define WS_AMP 10
#define WS_T 16
#define WS_M 24                        // 10 matrices x 4 -> 24..63
#define WS_CW0 64                      // 882 -> ends 946
#define WS_L1 948                      // 5 floats
#define WS_L2 956                      // 5 floats
#define WS_CH   1024                   // 317*884 = 280228 -> ends 281252
#define WS_DH   281344                 // 317*884 -> ends 561572
#define WS_CH0  561600                 // 884 -> ends 562484
// BR arrays reuse low region (KS finished before BR starts); DH dead after kB
#define WS_BRD  1024                   // 2*BRC
#define WS_BRS  (WS_BRD + 2*BRC)       // 2*BRC
#define WS_XT1  (WS_BRS + 2*BRC)       // BRC
#define WS_XT2  (WS_XT1 + BRC)         // BRC -> ends 394240

// ---------------- K0: coefficients only (tiny) ------------------------------
__global__ void k0_setup(const float* __restrict__ h,
                         const float* __restrict__ envp,
                         const float* __restrict__ lp2c,
                         float* __restrict__ ws) {
    if (blockIdx.x != 0 || threadIdx.x != 0) return;
    float h0=h[0], h1=h[1], h2=h[2], h3=h[3], h4=h[4], h5=h[5], h6=h[6];
    float decay = fminf(fmaxf(h0 / 10.0f + 0.9f, 0.9f), 0.999f);
    ws[WS_D2] = decay * 0.5f;
    ws[WS_FA] = h3;
    {
        float freq = fminf(fmaxf(h1 * (SRF/4.0f), 100.0f), SRF/2.0f - 1.0f);
        float q    = fminf(fmaxf(h2, 0.1f), 0.999f);
        float w0 = TWO_PI * freq / SRF;
        float sw = sinf(w0), cw = cosf(w0);
        float alpha = sw / (2.0f * q);
        float b0 = (1.0f - cw) * 0.5f, b1 = 1.0f - cw, b2 = b0;
        float a0 = 1.0f + alpha, a1 = -2.0f * cw, a2 = 1.0f - alpha;
        ws[WS_L1+0]=b0/a0; ws[WS_L1+1]=b1/a0; ws[WS_L1+2]=b2/a0;
        ws[WS_L1+3]=a1/a0; ws[WS_L1+4]=a2/a0;
    }
    {
        float freq = 100.0f + lp2c[0]*8000.0f;
        float q = 0.707f;
        float w0 = TWO_PI * freq / SRF;
        float sw = sinf(w0), cw = cosf(w0);
        float alpha = sw / (2.0f * q);
        float b0 = (1.0f - cw) * 0.5f, b1 = 1.0f - cw, b2 = b0;
        float a0 = 1.0f + alpha, a1 = -2.0f * cw, a2 = 1.0f - alpha;
        ws[WS_L2+0]=b0/a0; ws[WS_L2+1]=b1/a0; ws[WS_L2+2]=b2/a0;
        ws[WS_L2+3]=a1/a0; ws[WS_L2+4]=a2/a0;
    }
    {
        float freq = fminf(fmaxf(h5*(SRF/4.0f), 100.0f), SRF/2.0f - 1.0f);
        float q = fminf(fmaxf(h6, 0.1f), 0.999f);
        float w0 = TWO_PI * freq / SRF;
        float sw = sinf(w0), cw = cosf(w0);
        float alpha = sw / (2.0f * q);
        float b0 = 1.0f, b1 = -2.0f*cw, b2 = 1.0f;
        float a0 = 1.0f + alpha, a1 = -2.0f*cw, a2 = 1.0f - alpha;
        ws[WS_B0]=b0/a0; ws[WS_B1]=b1/a0; ws[WS_B2]=b2/a0;
        float A1=a1/a0, A2=a2/a0;
        ws[WS_A1]=A1; ws[WS_A2]=A2;
        float t00=-A1, t01=-A2, t10=1.0f, t11=0.0f;
        for (int k=0;k<7;k++){
            float na=t00*t00+t01*t10, nb=t00*t01+t01*t11;
            float nc=t10*t00+t11*t10, nd=t10*t01+t11*t11;
            t00=na;t01=nb;t10=nc;t11=nd;
        }
        ws[WS_T+0]=t00; ws[WS_T+1]=t01; ws[WS_T+2]=t10; ws[WS_T+3]=t11;
        for (int k=0;k<6;k++){
            float na=t00*t00+t01*t10, nb=t00*t01+t01*t11;
            float nc=t10*t00+t11*t10, nd=t10*t01+t11*t11;
            t00=na;t01=nb;t10=nc;t11=nd;
        }
        for (int k=0;k<10;k++){
            ws[WS_M+4*k+0]=t00; ws[WS_M+4*k+1]=t01;
            ws[WS_M+4*k+2]=t10; ws[WS_M+4*k+3]=t11;
            float na=t00*t00+t01*t10, nb=t00*t01+t01*t11;
            float nc=t10*t00+t11*t10, nd=t10*t01+t11*t11;
            t00=na;t01=nb;t10=nc;t11=nd;
        }
    }
    {
        float nF = (float)NS;
        float attack  = 1.0f + envp[0]*0.1f*nF;
        float release = 1.0f + envp[2]*0.1f*nF;
        ws[WS_INVA] = 1.0f/attack;
        ws[WS_INVR] = 1.0f/release;
        ws[WS_SUS]  = fminf(fmaxf(envp[1], 0.0f), 1.0f);
        ws[WS_AMP]  = h4;
    }
}

// resolvent g_n of y_n = -a1 y_{n-1} - a2 y_{n-2}, g_0=1, g_1=-a1
__device__ float resolvent(float a1f, float a2f, int n) {
    double a1 = (double)a1f, a2 = (double)a2f;
    double disc = a1*a1 - 4.0*a2;
    double scale = a1*a1 + 4.0*fabs(a2) + 1e-30;
    if (disc > 1e-9*scale) {
        double sq = sqrt(disc);
        double p1 = 0.5*(-a1+sq), p2 = 0.5*(-a1-sq);
        int k = n+1;
        double t1 = pow(fabs(p1), (double)k); if (p1 < 0.0 && (k&1)) t1 = -t1;
        double t2 = pow(fabs(p2), (double)k); if (p2 < 0.0 && (k&1)) t2 = -t2;
        return (float)((t1 - t2)/sq);
    } else if (disc < -1e-9*scale) {
        double r = sqrt(a2);
        double ct = -a1/(2.0*r);
        ct = fmin(1.0, fmax(-1.0, ct));
        double th = acos(ct);
        double sth = sin(th);
        double rn = pow(r, (double)n);
        return (float)(rn * sin((double)(n+1)*th) / sth);
    } else {
        double p = -0.5*a1;
        double t = pow(fabs(p), (double)n); if (p < 0.0 && (n&1)) t = -t;
        return (float)((double)(n+1)*t);
    }
}

// ---------------- K0b: wavetable cascade filter + forward DFT -> CH0 --------
__global__ __launch_bounds__(896) void k0b_wt(const float* __restrict__ wt,
                                              float* __restrict__ ws) {
    __shared__ float sx[W], sg[W], su[W], sy[W];
    const int i = threadIdx.x;
    const float b10=ws[WS_L1+0], b11=ws[WS_L1+1], b12=ws[WS_L1+2];
    const float a11=ws[WS_L1+3], a12=ws[WS_L1+4];
    const float b20=ws[WS_L2+0], b21=ws[WS_L2+1], b22=ws[WS_L2+2];
    const float a21=ws[WS_L2+3], a22=ws[WS_L2+4];
    if (i < W) { sx[i] = wt[i]; sg[i] = resolvent(a11, a12, i); }
    __syncthreads();
    if (i < W) {
        float acc = 0.0f;
        for (int k = 0; k <= i; k++) acc += sg[k]*sx[i-k];
        su[i] = acc;
    }
    __syncthreads();
    if (i < W) {
        float y = b10*su[i];
        if (i >= 1) y += b11*su[i-1];
        if (i >= 2) y += b12*su[i-2];
        sy[i] = y;
        sg[i] = resolvent(a21, a22, i);
    }
    __syncthreads();
    if (i < W) {
        float acc = 0.0f;
        for (int k = 0; k <= i; k++) acc += sg[k]*sy[i-k];
        su[i] = acc;
    }
    __syncthreads();
    if (i < W) {
        float y = b20*su[i];
        if (i >= 1) y += b21*su[i-1];
        if (i >= 2) y += b22*su[i-2];
        ws[WS_CW0 + i] = y;
        sy[i] = y;
    }
    __syncthreads();
    // fold: su = even part, sg = odd part
    if (i < NHALF) { su[i] = sy[i] + sy[i+NHALF]; sg[i] = sy[i] - sy[i+NHALF]; }
    __syncthreads();
    if (i < NFREQ) {
        const int f = i;
        const float* yb = (f & 1) ? sg : su;
        float ang = (float)f * (TWO_PI / (float)W);
        float S, C; __sincosf(ang, &S, &C);
        float cr = 1.0f, ci = 0.0f;      // e^{-i phi f k} at k=0
        float re = 0.0f, im = 0.0f;
        for (int k = 0; k < NHALF; k++) {
            float y = yb[k];
            re = fmaf(y, cr, re);
            im = fmaf(y, ci, im);
            float t = cr;
            cr = fmaf(t, C,  ci*S);      // *(C - iS)
            ci = fmaf(ci, C, -t*S);
        }
        ws[WS_CH0 + 2*f]   = re;
        ws[WS_CH0 + 2*f+1] = im;
    }
}

// ---------------- K1: KS pass A — 448 thr, 2 samples/thread + fwd DFT -------
__global__ __launch_bounds__(448) void k1_ksA(const float* __restrict__ fb,
                                              float* __restrict__ ws) {
    __shared__ float sv[W], se[NHALF], so[NHALF];
    __shared__ float sbb[2][8];
    const int t = threadIdx.x;
    const int lane = t & 63, wv = t >> 6;
    const int g = blockIdx.x;
    const float d2 = ws[WS_D2], fa = ws[WS_FA];
    const bool act = (t < NHALF);
    const float* fbp2 = fb + (long)g*MCH*W + 2*t;
    float z0 = 0.0f, z1 = 0.0f;
    float2 cur = act ? *(const float2*)fbp2 : make_float2(0.f,0.f);
    for (int j = 0; j < MCH; j++) {
        float2 nxt = make_float2(0.f,0.f);
        if (j+1 < MCH && act) nxt = *(const float2*)(fbp2 + (long)(j+1)*W);
        float v0 = z0 + tanhf(fa*cur.x);
        float v1 = z1 + tanhf(fa*cur.y);
        if (lane == 63 && wv < 6) sbb[j&1][wv+1] = v1;
        if (t == NHALF-1)         sbb[j&1][0]    = v1;
        float vs = __shfl_up(v1, 1);
        __syncthreads();
        float vp = (lane == 0) ? sbb[j&1][wv] : vs;
        z0 = d2*(v0 + vp);
        z1 = d2*(v1 + v0);
        cur = nxt;
    }
    if (act) { sv[2*t] = z0; sv[2*t+1] = z1; }
    __syncthreads();
    if (t < NHALF) { se[t] = sv[t] + sv[t+NHALF]; so[t] = sv[t] - sv[t+NHALF]; }
    __syncthreads();
    if (t < NFREQ) {
        const int f = t;
        const float* yb = (f & 1) ? so : se;
        float ang = (float)f * (TWO_PI / (float)W);
        float S, C; __sincosf(ang, &S, &C);
        float cr = 1.0f, ci = 0.0f;
        float re = 0.0f, im = 0.0f;
        for (int k = 0; k < NHALF; k++) {
            float y = yb[k];
            re = fmaf(y, cr, re);
            im = fmaf(y, ci, im);
            float tt = cr;
            cr = fmaf(tt, C,  ci*S);
            ci = fmaf(ci, C, -tt*S);
        }
        float* dst = ws + WS_DH + (long)g*(2*NFREQ);
        dst[2*f]   = re;
        dst[2*f+1] = im;
    }
}

// ---------------- KB: per-frequency scan over chunks (unroll-4) -------------
__global__ __launch_bounds__(64) void kB_scan(float* __restrict__ ws) {
    const int f = blockIdx.x*64 + threadIdx.x;
    if (f >= NFREQ) return;
    const float d2 = ws[WS_D2];
    double phi = (double)f * (double)(TWO_PI) / (double)W;
    double m2 = 2.0 * (double)d2 * cos(0.5*phi);
    double mag = pow(m2, (double)MCH);
    double ang = -0.5 * (double)MCH * phi;
    float mre = (float)(mag * cos(ang));
    float mim = (float)(mag * sin(ang));
    float cre = ws[WS_CH0 + 2*f];
    float cim = ws[WS_CH0 + 2*f+1];
    float* CH = ws + WS_CH;
    CH[2*f] = cre; CH[2*f+1] = cim;
    const float* DH = ws + WS_DH;
    // 316 iterations = 79 * 4 exactly (g = 1..316)
    for (int g = 1; g < G_CH; g += 4) {
        float dr[4], di[4];
        #pragma unroll
        for (int u = 0; u < 4; u++) {
            dr[u] = DH[(long)(g-1+u)*(2*NFREQ) + 2*f];
            di[u] = DH[(long)(g-1+u)*(2*NFREQ) + 2*f+1];
        }
        #pragma unroll
        for (int u = 0; u < 4; u++) {
            float nre = mre*cre - mim*cim + dr[u];
            float nim = mre*cim + mim*cre + di[u];
            cre = nre; cim = nim;
            CH[(long)(g+u)*(2*NFREQ) + 2*f]   = cre;
            CH[(long)(g+u)*(2*NFREQ) + 2*f+1] = cim;
        }
    }
}

// ---------------- K3: folded rotation-IDFT + outputs + tail fade ------------
// 448 threads; thread j<441 computes cini pair (j, j+441); time loop 2 samp/thr
__global__ __launch_bounds__(448) void k3_ksC(const float* __restrict__ fb,
                                              const float* __restrict__ ws,
                                              float* __restrict__ out) {
    __shared__ float chs[2*NFREQ];
    __shared__ float cini[W];
    __shared__ float sbb[2][8];
    const int t = threadIdx.x;
    const int lane = t & 63, wv = t >> 6;
    const int g = blockIdx.x;
    const float d2 = ws[WS_D2], fa = ws[WS_FA];
    const bool act = (t < NHALF);
    {
        const float* src = ws + WS_CH + (long)g*(2*NFREQ);
        if (t < NFREQ) { chs[2*t] = src[2*t]; chs[2*t+1] = src[2*t+1]; }
    }
    __syncthreads();
    // folded IDFT: j & j+441 share one 220-iter rotor chain (step e^{i*2*phi*j})
    if (act) {
        const int j = t;
        float aj = (float)j * (TWO_PI / (float)W);
        float sA, cA; __sincosf(aj, &sA, &cA);          // e^{i a_j}
        float s2, c2; __sincosf(2.0f*aj, &s2, &c2);     // rotor step
        float rr = 1.0f, ri = 0.0f;                     // sigma^m, m=0
        float RE = 0.0f, SOr = 0.0f, SOi = 0.0f;
        for (int m = 0; m < 220; m++) {
            float xr = chs[4*m+2], xi = chs[4*m+3];     // X_{2m+1}
            SOr = fmaf(xr, rr, SOr); SOr = fmaf(-xi, ri, SOr);
            SOi = fmaf(xr, ri, SOi); SOi = fmaf( xi, rr, SOi);
            float tr = rr;
            rr = fmaf(tr, c2, -ri*s2);
            ri = fmaf(ri, c2,  tr*s2);
            float yr = chs[4*m+4], yi = chs[4*m+5];     // X_{2m+2}
            RE = fmaf(yr, rr, RE); RE = fmaf(-yi, ri, RE);
        }
        float RO = cA*SOr - sA*SOi;
        float sgn = (j & 1) ? -1.0f : 1.0f;
        float base0 = chs[0] + sgn*chs[2*NHALF];
        float base1 = chs[0] - sgn*chs[2*NHALF];
        cini[j]        = (base0 + 2.0f*(RE + RO)) * (1.0f/(float)W);
        cini[j+NHALF]  = (base1 + 2.0f*(RE - RO)) * (1.0f/(float)W);
    }
    __syncthreads();
    float z0 = act ? cini[2*t]   : 0.0f;
    float z1 = act ? cini[2*t+1] : 0.0f;
    const float* fbp2 = fb + (long)g*MCH*W + 2*t;
    float* outp2 = out + (long)g*MCH*W + 2*t;
    float2 cur = act ? *(const float2*)fbp2 : make_float2(0.f,0.f);
    for (int j = 0; j < MCH; j++) {
        float2 nxt = make_float2(0.f,0.f);
        if (j+1 < MCH && act) nxt = *(const float2*)(fbp2 + (long)(j+1)*W);
        float v0 = z0 + tanhf(fa*cur.x);
        float v1 = z1 + tanhf(fa*cur.y);
        if (lane == 63 && wv < 6) sbb[j&1][wv+1] = v1;
        if (t == NHALF-1)         sbb[j&1][0]    = v1;
        float vs = __shfl_up(v1, 1);
        __syncthreads();
        float vp = (lane == 0) ? sbb[j&1][wv] : vs;
        z0 = d2*(v0 + vp);
        z1 = d2*(v1 + v0);
        if (act) *(float2*)(outp2 + (long)j*W) = make_float2(z0, z1);
        cur = nxt;
    }
    if (g == G_CH-1) {
        // one decay step w/o feedback, first 788 samples, fade tail
        float v0 = z0, v1 = z1;
        if (lane == 63 && wv < 6) sbb[0][wv+1] = v1;
        if (t == NHALF-1)         sbb[0][0]    = v1;
        float vs = __shfl_up(v1, 1);
        __syncthreads();
        float vp = (lane == 0) ? sbb[0][wv] : vs;
        float r0 = d2*(v0 + vp);
        float r1 = d2*(v1 + v0);
        if (t < REMN/2) {
            int idx0 = REMSTART + 2*t;
            int idx1 = idx0 + 1;
            if (idx0 >= NS-256) r0 *= (1.0f - (float)(idx0-(NS-256))*(1.0f/255.0f));
            if (idx1 >= NS-256) r1 *= (1.0f - (float)(idx1-(NS-256))*(1.0f/255.0f));
            *(float2*)(out + idx0) = make_float2(r0, r1);
        }
    }
}

// ---------------- K4: BR pass 1 — zero-y-state chunk offsets ----------------
__global__ __launch_bounds__(256) void k4_br1(const float* __restrict__ x,
                                              float* __restrict__ ws) {
    __shared__ float tile[256*33];
    const int tid = threadIdx.x;
    const int c = blockIdx.x*256 + tid;
    const long base = (long)blockIdx.x * (256*BRL);
    const float B0=ws[WS_B0],B1=ws[WS_B1],B2=ws[WS_B2],A1=ws[WS_A1],A2=ws[WS_A2];
    float x1, x2, y1=0.f, y2=0.f;
    {
        long g0 = (long)c * BRL;
        x1 = (c>0) ? x[g0-1] : 0.0f;
        x2 = (c>0) ? x[g0-2] : 0.0f;
    }
    for (int tt=0; tt<BRL/32; tt++) {
        const float4* src4 = (const float4*)(x + base + (long)tt*32);
        for (int q = tid; q < 256*8; q += 256) {
            int r = q >> 3, c4 = q & 7;
            float4 v = src4[(long)r*(BRL/4) + c4];
            tile[r*33 + c4*4 + 0] = v.x;
            tile[r*33 + c4*4 + 1] = v.y;
            tile[r*33 + c4*4 + 2] = v.z;
            tile[r*33 + c4*4 + 3] = v.w;
        }
        __syncthreads();
        #pragma unroll
        for (int j=0;j<32;j++){
            float xv = tile[tid*33 + j];
            float y = B0*xv + B1*x1 + B2*x2 - A1*y1 - A2*y2;
            x2=x1; x1=xv; y2=y1; y1=y;
        }
        __syncthreads();
    }
    ws[WS_BRD + 2*c]   = y1;
    ws[WS_BRD + 2*c+1] = y2;
    ws[WS_XT1 + c] = x1;
    ws[WS_XT2 + c] = x2;
}

// ---------------- K5: BR pass 2 — single-block state scan -------------------
__global__ __launch_bounds__(1024) void k5_scan(float* __restrict__ ws) {
    __shared__ float sa[1024], sb[1024];
    const int t = threadIdx.x;
    const float T00=ws[WS_T+0],T01=ws[WS_T+1],T10=ws[WS_T+2],T11=ws[WS_T+3];
    float m[10][4];
    #pragma unroll
    for (int k=0;k<10;k++){
        m[k][0]=ws[WS_M+4*k+0]; m[k][1]=ws[WS_M+4*k+1];
        m[k][2]=ws[WS_M+4*k+2]; m[k][3]=ws[WS_M+4*k+3];
    }
    float e1=0.f, e2=0.f;
    const long rb = (long)t * SCAN_R;
    for (int r=0;r<SCAN_R;r+=4){
        float d1v[4], d2v[4];
        #pragma unroll
        for (int u=0;u<4;u++){
            d1v[u] = ws[WS_BRD + 2*(rb+r+u)];
            d2v[u] = ws[WS_BRD + 2*(rb+r+u)+1];
        }
        #pragma unroll
        for (int u=0;u<4;u++){
            float n1 = T00*e1 + T01*e2 + d1v[u];
            float n2 = T10*e1 + T11*e2 + d2v[u];
            e1=n1; e2=n2;
        }
    }
    float s1=e1, s2=e2;
    #pragma unroll
    for (int k=0;k<10;k++){
        sa[t]=s1; sb[t]=s2;
        __syncthreads();
        int off = 1<<k;
        float p1=0.f,p2=0.f;
        if (t >= off){ p1=sa[t-off]; p2=sb[t-off]; }
        __syncthreads();
        if (t >= off){
            s1 = s1 + m[k][0]*p1 + m[k][1]*p2;
            s2 = s2 + m[k][2]*p1 + m[k][3]*p2;
        }
    }
    sa[t]=s1; sb[t]=s2;
    __syncthreads();
    float y1 = (t>0)? sa[t-1] : 0.0f;
    float y2 = (t>0)? sb[t-1] : 0.0f;
    for (int r=0;r<SCAN_R;r+=4){
        float d1v[4], d2v[4];
        #pragma unroll
        for (int u=0;u<4;u++){
            d1v[u] = ws[WS_BRD + 2*(rb+r+u)];
            d2v[u] = ws[WS_BRD + 2*(rb+r+u)+1];
        }
        #pragma unroll
        for (int u=0;u<4;u++){
            long c = rb + r + u;
            ws[WS_BRS + 2*c]   = y1;
            ws[WS_BRS + 2*c+1] = y2;
            float n1 = T00*y1 + T01*y2 + d1v[u];
            float n2 = T10*y1 + T11*y2 + d2v[u];
            y1=n1; y2=n2;
        }
    }
}

// ---------------- K6: BR pass 3 — true outputs + envelope, in-place ---------
__global__ __launch_bounds__(256) void k6_br2(float* __restrict__ x,
                                              const float* __restrict__ ws) {
    __shared__ float tile[256*33];
    const int tid = threadIdx.x;
    const int c = blockIdx.x*256 + tid;
    const long base = (long)blockIdx.x * (256*BRL);
    const float B0=ws[WS_B0],B1=ws[WS_B1],B2=ws[WS_B2],A1=ws[WS_A1],A2=ws[WS_A2];
    const float invA=ws[WS_INVA], invR=ws[WS_INVR];
    const float sa_ = ws[WS_SUS]*ws[WS_AMP];
    float x1 = (c>0)? ws[WS_XT1 + c-1] : 0.0f;
    float x2 = (c>0)? ws[WS_XT2 + c-1] : 0.0f;
    float y1 = ws[WS_BRS + 2*c];
    float y2 = ws[WS_BRS + 2*c+1];
    for (int tt=0; tt<BRL/32; tt++) {
        float4* dst4 = (float4*)(x + base + (long)tt*32);
        for (int q = tid; q < 256*8; q += 256) {
            int r = q >> 3, c4 = q & 7;
            float4 v = ((const float4*)dst4)[(long)r*(BRL/4) + c4];
            tile[r*33 + c4*4 + 0] = v.x;
            tile[r*33 + c4*4 + 1] = v.y;
            tile[r*33 + c4*4 + 2] = v.z;
            tile[r*33 + c4*4 + 3] = v.w;
        }
        __syncthreads();
        #pragma unroll
        for (int j=0;j<32;j++){
            float xv = tile[tid*33 + j];
            float y = B0*xv + B1*x1 + B2*x2 - A1*y1 - A2*y2;
            x2=x1; x1=xv; y2=y1; y1=y;
            int idx = c*BRL + tt*32 + j;
            float ea = fminf((float)idx * invA, 1.0f);
            float er = fminf((float)(NS-1-idx) * invR, 1.0f);
            tile[tid*33 + j] = y * (ea*er*sa_);
        }
        __syncthreads();
        for (int q = tid; q < 256*8; q += 256) {
            int r = q >> 3, c4 = q & 7;
            float4 v;
            v.x = tile[r*33 + c4*4 + 0];
            v.y = tile[r*33 + c4*4 + 1];
            v.z = tile[r*33 + c4*4 + 2];
            v.w = tile[r*33 + c4*4 + 3];
            dst4[(long)r*(BRL/4) + c4] = v;
        }
        __syncthreads();
    }
}

extern "C" void kernel_launch(void* const* d_in, const int* in_sizes, int n_in,
                              void* d_out, int out_size, void* d_ws, size_t ws_size,
                              hipStream_t stream) {
    const float* fb   = (const float*)d_in[0];
    const float* wt   = (const float*)d_in[1];
    const float* h    = (const float*)d_in[2];
    const float* envp = (const float*)d_in[3];
    const float* lp2c = (const float*)d_in[4];
    float* out = (float*)d_out;
    float* ws  = (float*)d_ws;

    hipLaunchKernelGGL(k0_setup, dim3(1),    dim3(64),   0, stream, h, envp, lp2c, ws);
    hipLaunchKernelGGL(k0b_wt,   dim3(1),    dim3(896),  0, stream, wt, ws);
    hipLaunchKernelGGL(k1_ksA,   dim3(G_CH), dim3(448),  0, stream, fb, ws);
    hipLaunchKernelGGL(kB_scan,  dim3(7),    dim3(64),   0, stream, ws);
    hipLaunchKernelGGL(k3_ksC,   dim3(G_CH), dim3(448),  0, stream, fb, ws, out);
    hipLaunchKernelGGL(k4_br1,   dim3(256),  dim3(256),  0, stream, out, ws);
    hipLaunchKernelGGL(k5_scan,  dim3(1),    dim3(1024), 0, stream, ws);
    hipLaunchKernelGGL(k6_br2,   dim3(256),  dim3(256),  0, stream, out, ws);
}

// Round 7
// 231.518 us; speedup vs baseline: 2.1224x; 1.3968x over previous
//
#include <hip/hip_runtime.h>
#include <math.h>

#define SRF 44100.0f
#define TWO_PI 6.283185307179586f
#define W 882
#define NHALF 441
#define NFREQ 442
#define MCH 30
#define G_CH 317
#define NS 8388608
#define REMSTART 8387820
#define REMN 788
#define BRL 128
#define BRC 65536
#define WDEPTH 32

// ---- ws float layout ----
#define WS_CH   1024                   // 317*884 = 280228 -> ends 281252
#define WS_DH   281344                 // 317*884 -> ends 561572
#define WS_CH0  561600                 // 884 -> ends 562484
// BR arrays reuse low region (KS finished before BR starts); DH dead after kB
#define WS_BRD  1024                   // 2*BRC
#define WS_BRS  (WS_BRD + 2*BRC)       // 2*BRC
#define WS_XT1  (WS_BRS + 2*BRC)       // BRC
#define WS_XT2  (WS_XT1 + BRC)         // BRC -> ends 394240

__device__ __forceinline__ float clipf(float x, float lo, float hi) {
    return fminf(fmaxf(x, lo), hi);
}

// resolvent g_n of y_n = -a1 y_{n-1} - a2 y_{n-2}, g_0=1, g_1=-a1
__device__ float resolvent(float a1f, float a2f, int n) {
    double a1 = (double)a1f, a2 = (double)a2f;
    double disc = a1*a1 - 4.0*a2;
    double scale = a1*a1 + 4.0*fabs(a2) + 1e-30;
    if (disc > 1e-9*scale) {
        double sq = sqrt(disc);
        double p1 = 0.5*(-a1+sq), p2 = 0.5*(-a1-sq);
        int k = n+1;
        double t1 = pow(fabs(p1), (double)k); if (p1 < 0.0 && (k&1)) t1 = -t1;
        double t2 = pow(fabs(p2), (double)k); if (p2 < 0.0 && (k&1)) t2 = -t2;
        return (float)((t1 - t2)/sq);
    } else if (disc < -1e-9*scale) {
        double r = sqrt(a2);
        double ct = -a1/(2.0*r);
        ct = fmin(1.0, fmax(-1.0, ct));
        double th = acos(ct);
        double sth = sin(th);
        double rn = pow(r, (double)n);
        return (float)(rn * sin((double)(n+1)*th) / sth);
    } else {
        double p = -0.5*a1;
        double t = pow(fabs(p), (double)n); if (p < 0.0 && (n&1)) t = -t;
        return (float)((double)(n+1)*t);
    }
}

// ---------------- K1: blocks 0..316 = KS deltas + fwd DFT; block 317 = wavetable
__global__ __launch_bounds__(448) void k1_ksA(const float* __restrict__ fb,
                                              const float* __restrict__ wt,
                                              const float* __restrict__ h,
                                              const float* __restrict__ lp2c,
                                              float* __restrict__ ws) {
    __shared__ float sv[W], se[NHALF], so[NHALF];
    __shared__ float sbb[2][8];
    __shared__ float sx[W], sg[W], su[W], sy[W];
    const int t = threadIdx.x;
    const int g = blockIdx.x;

    if (g == G_CH) {
        // ---- wavetable cascade filter + forward DFT -> CH0 ----
        float b10,b11,b12,a11,a12, b20,b21,b22,a21,a22;
        {
            float freq = clipf(h[1] * (SRF/4.0f), 100.0f, SRF/2.0f - 1.0f);
            float q    = clipf(h[2], 0.1f, 0.999f);
            float w0 = TWO_PI * freq / SRF;
            float sw = sinf(w0), cw = cosf(w0);
            float alpha = sw / (2.0f * q);
            float b0 = (1.0f - cw) * 0.5f, b1 = 1.0f - cw, b2 = b0;
            float a0 = 1.0f + alpha, a1 = -2.0f * cw, a2 = 1.0f - alpha;
            b10=b0/a0; b11=b1/a0; b12=b2/a0; a11=a1/a0; a12=a2/a0;
        }
        {
            float freq = 100.0f + lp2c[0]*8000.0f;
            float q = 0.707f;
            float w0 = TWO_PI * freq / SRF;
            float sw = sinf(w0), cw = cosf(w0);
            float alpha = sw / (2.0f * q);
            float b0 = (1.0f - cw) * 0.5f, b1 = 1.0f - cw, b2 = b0;
            float a0 = 1.0f + alpha, a1 = -2.0f * cw, a2 = 1.0f - alpha;
            b20=b0/a0; b21=b1/a0; b22=b2/a0; a21=a1/a0; a22=a2/a0;
        }
        const int i0 = t, i1 = t + NHALF;
        if (t < NHALF) {
            sx[i0] = wt[i0]; sx[i1] = wt[i1];
            sg[i0] = resolvent(a11, a12, i0);
            sg[i1] = resolvent(a11, a12, i1);
        }
        __syncthreads();
        if (t < NHALF) {
            float acc = 0.0f;
            for (int k = 0; k <= i0; k++) acc += sg[k]*sx[i0-k];
            su[i0] = acc;
            acc = 0.0f;
            for (int k = 0; k <= i1; k++) acc += sg[k]*sx[i1-k];
            su[i1] = acc;
        }
        __syncthreads();
        if (t < NHALF) {
            float y = b10*su[i0];
            if (i0 >= 1) y += b11*su[i0-1];
            if (i0 >= 2) y += b12*su[i0-2];
            sy[i0] = y;
            y = b20*su[i1-0]*0.0f; // placeholder avoided below
            y = b10*su[i1] + b11*su[i1-1] + b12*su[i1-2];
            sy[i1] = y;
            sg[i0] = resolvent(a21, a22, i0);
            sg[i1] = resolvent(a21, a22, i1);
        }
        __syncthreads();
        if (t < NHALF) {
            float acc = 0.0f;
            for (int k = 0; k <= i0; k++) acc += sg[k]*sy[i0-k];
            su[i0] = acc;
            acc = 0.0f;
            for (int k = 0; k <= i1; k++) acc += sg[k]*sy[i1-k];
            su[i1] = acc;
        }
        __syncthreads();
        if (t < NHALF) {
            float y = b20*su[i0];
            if (i0 >= 1) y += b21*su[i0-1];
            if (i0 >= 2) y += b22*su[i0-2];
            sv[i0] = y;
            y = b20*su[i1] + b21*su[i1-1] + b22*su[i1-2];
            sv[i1] = y;
        }
        __syncthreads();
        if (t < NHALF) { se[t] = sv[t] + sv[t+NHALF]; so[t] = sv[t] - sv[t+NHALF]; }
        __syncthreads();
        if (t < NFREQ) {
            const int f = t;
            const float* yb = (f & 1) ? so : se;
            float ang = (float)f * (TWO_PI / (float)W);
            float S, C; __sincosf(ang, &S, &C);
            float cr = 1.0f, ci = 0.0f;
            float re = 0.0f, im = 0.0f;
            for (int k = 0; k < NHALF; k++) {
                float y = yb[k];
                re = fmaf(y, cr, re);
                im = fmaf(y, ci, im);
                float tt = cr;
                cr = fmaf(tt, C,  ci*S);
                ci = fmaf(ci, C, -tt*S);
            }
            ws[WS_CH0 + 2*f]   = re;
            ws[WS_CH0 + 2*f+1] = im;
        }
        return;
    }

    // ---- KS zero-state delta + forward DFT ----
    const float decay = clipf(h[0] / 10.0f + 0.9f, 0.9f, 0.999f);
    const float d2 = decay * 0.5f;
    const float fa = h[3];
    const int lane = t & 63, wv = t >> 6;
    const bool act = (t < NHALF);
    const float* fbp2 = fb + (long)g*MCH*W + 2*t;
    float z0 = 0.0f, z1 = 0.0f;
    float2 cur = act ? *(const float2*)fbp2 : make_float2(0.f,0.f);
    for (int j = 0; j < MCH; j++) {
        float2 nxt = make_float2(0.f,0.f);
        if (j+1 < MCH && act) nxt = *(const float2*)(fbp2 + (long)(j+1)*W);
        float v0 = z0 + tanhf(fa*cur.x);
        float v1 = z1 + tanhf(fa*cur.y);
        if (lane == 63 && wv < 6) sbb[j&1][wv+1] = v1;
        if (t == NHALF-1)         sbb[j&1][0]    = v1;
        float vs = __shfl_up(v1, 1);
        __syncthreads();
        float vp = (lane == 0) ? sbb[j&1][wv] : vs;
        z0 = d2*(v0 + vp);
        z1 = d2*(v1 + v0);
        cur = nxt;
    }
    if (act) { sv[2*t] = z0; sv[2*t+1] = z1; }
    __syncthreads();
    if (t < NHALF) { se[t] = sv[t] + sv[t+NHALF]; so[t] = sv[t] - sv[t+NHALF]; }
    __syncthreads();
    if (t < NFREQ) {
        const int f = t;
        const float* yb = (f & 1) ? so : se;
        float ang = (float)f * (TWO_PI / (float)W);
        float S, C; __sincosf(ang, &S, &C);
        float cr = 1.0f, ci = 0.0f;
        float re = 0.0f, im = 0.0f;
        for (int k = 0; k < NHALF; k++) {
            float y = yb[k];
            re = fmaf(y, cr, re);
            im = fmaf(y, ci, im);
            float tt = cr;
            cr = fmaf(tt, C,  ci*S);
            ci = fmaf(ci, C, -tt*S);
        }
        float* dst = ws + WS_DH + (long)g*(2*NFREQ);
        dst[2*f]   = re;
        dst[2*f+1] = im;
    }
}

// ---------------- KB: per-frequency scan over chunks (8-deep pipeline) ------
__global__ __launch_bounds__(64) void kB_scan(const float* __restrict__ h,
                                              float* __restrict__ ws) {
    const int f = blockIdx.x*64 + threadIdx.x;
    if (f >= NFREQ) return;
    const float decay = clipf(h[0] / 10.0f + 0.9f, 0.9f, 0.999f);
    const float d2 = decay * 0.5f;
    double phi = (double)f * (double)(TWO_PI) / (double)W;
    double m2 = 2.0 * (double)d2 * cos(0.5*phi);
    double mag = pow(m2, (double)MCH);
    double ang = -0.5 * (double)MCH * phi;
    float mre = (float)(mag * cos(ang));
    float mim = (float)(mag * sin(ang));
    float cre = ws[WS_CH0 + 2*f];
    float cim = ws[WS_CH0 + 2*f+1];
    float* CH = ws + WS_CH;
    const float* DH = ws + WS_DH;
    CH[2*f] = cre; CH[2*f+1] = cim;
    // g = 1..316 ; 39 batches of 8 + tail 4
    float cr8[8], ci8[8], nr8[8], ni8[8];
    #pragma unroll
    for (int u = 0; u < 8; u++) {
        cr8[u] = DH[(long)u*(2*NFREQ) + 2*f];
        ci8[u] = DH[(long)u*(2*NFREQ) + 2*f+1];
    }
    for (int b = 0; b < 39; b++) {
        const int gnext = 1 + (b+1)*8;   // first g of next batch
        if (b < 38) {
            #pragma unroll
            for (int u = 0; u < 8; u++) {
                nr8[u] = DH[(long)(gnext-1+u)*(2*NFREQ) + 2*f];
                ni8[u] = DH[(long)(gnext-1+u)*(2*NFREQ) + 2*f+1];
            }
        } else {
            #pragma unroll
            for (int u = 0; u < 4; u++) {
                nr8[u] = DH[(long)(gnext-1+u)*(2*NFREQ) + 2*f];
                ni8[u] = DH[(long)(gnext-1+u)*(2*NFREQ) + 2*f+1];
            }
        }
        const int g0 = 1 + b*8;
        #pragma unroll
        for (int u = 0; u < 8; u++) {
            float nre = mre*cre - mim*cim + cr8[u];
            float nim = mre*cim + mim*cre + ci8[u];
            cre = nre; cim = nim;
            CH[(long)(g0+u)*(2*NFREQ) + 2*f]   = cre;
            CH[(long)(g0+u)*(2*NFREQ) + 2*f+1] = cim;
        }
        #pragma unroll
        for (int u = 0; u < 8; u++) { cr8[u] = nr8[u]; ci8[u] = ni8[u]; }
    }
    #pragma unroll
    for (int u = 0; u < 4; u++) {
        float nre = mre*cre - mim*cim + cr8[u];
        float nim = mre*cim + mim*cre + ci8[u];
        cre = nre; cim = nim;
        CH[(long)(313+u)*(2*NFREQ) + 2*f]   = cre;
        CH[(long)(313+u)*(2*NFREQ) + 2*f+1] = cim;
    }
}

// ---------------- K3: folded rotation-IDFT + outputs + tail fade ------------
__global__ __launch_bounds__(448) void k3_ksC(const float* __restrict__ fb,
                                              const float* __restrict__ h,
                                              const float* __restrict__ ws,
                                              float* __restrict__ out) {
    __shared__ float chs[2*NFREQ];
    __shared__ float cini[W];
    __shared__ float sbb[2][8];
    const int t = threadIdx.x;
    const int lane = t & 63, wv = t >> 6;
    const int g = blockIdx.x;
    const float decay = clipf(h[0] / 10.0f + 0.9f, 0.9f, 0.999f);
    const float d2 = decay * 0.5f;
    const float fa = h[3];
    const bool act = (t < NHALF);
    {
        const float* src = ws + WS_CH + (long)g*(2*NFREQ);
        if (t < NFREQ) { chs[2*t] = src[2*t]; chs[2*t+1] = src[2*t+1]; }
    }
    __syncthreads();
    if (act) {
        const int j = t;
        float aj = (float)j * (TWO_PI / (float)W);
        float sA, cA; __sincosf(aj, &sA, &cA);
        float s2, c2; __sincosf(2.0f*aj, &s2, &c2);
        float rr = 1.0f, ri = 0.0f;
        float RE = 0.0f, SOr = 0.0f, SOi = 0.0f;
        for (int m = 0; m < 220; m++) {
            float xr = chs[4*m+2], xi = chs[4*m+3];
            SOr = fmaf(xr, rr, SOr); SOr = fmaf(-xi, ri, SOr);
            SOi = fmaf(xr, ri, SOi); SOi = fmaf( xi, rr, SOi);
            float tr = rr;
            rr = fmaf(tr, c2, -ri*s2);
            ri = fmaf(ri, c2,  tr*s2);
            float yr = chs[4*m+4], yi = chs[4*m+5];
            RE = fmaf(yr, rr, RE); RE = fmaf(-yi, ri, RE);
        }
        float RO = cA*SOr - sA*SOi;
        float sgn = (j & 1) ? -1.0f : 1.0f;
        float base0 = chs[0] + sgn*chs[2*NHALF];
        float base1 = chs[0] - sgn*chs[2*NHALF];
        cini[j]        = (base0 + 2.0f*(RE + RO)) * (1.0f/(float)W);
        cini[j+NHALF]  = (base1 + 2.0f*(RE - RO)) * (1.0f/(float)W);
    }
    __syncthreads();
    float z0 = act ? cini[2*t]   : 0.0f;
    float z1 = act ? cini[2*t+1] : 0.0f;
    const float* fbp2 = fb + (long)g*MCH*W + 2*t;
    float* outp2 = out + (long)g*MCH*W + 2*t;
    float2 cur = act ? *(const float2*)fbp2 : make_float2(0.f,0.f);
    for (int j = 0; j < MCH; j++) {
        float2 nxt = make_float2(0.f,0.f);
        if (j+1 < MCH && act) nxt = *(const float2*)(fbp2 + (long)(j+1)*W);
        float v0 = z0 + tanhf(fa*cur.x);
        float v1 = z1 + tanhf(fa*cur.y);
        if (lane == 63 && wv < 6) sbb[j&1][wv+1] = v1;
        if (t == NHALF-1)         sbb[j&1][0]    = v1;
        float vs = __shfl_up(v1, 1);
        __syncthreads();
        float vp = (lane == 0) ? sbb[j&1][wv] : vs;
        z0 = d2*(v0 + vp);
        z1 = d2*(v1 + v0);
        if (act) *(float2*)(outp2 + (long)j*W) = make_float2(z0, z1);
        cur = nxt;
    }
    if (g == G_CH-1) {
        float v0 = z0, v1 = z1;
        if (lane == 63 && wv < 6) sbb[0][wv+1] = v1;
        if (t == NHALF-1)         sbb[0][0]    = v1;
        float vs = __shfl_up(v1, 1);
        __syncthreads();
        float vp = (lane == 0) ? sbb[0][wv] : vs;
        float r0 = d2*(v0 + vp);
        float r1 = d2*(v1 + v0);
        if (t < REMN/2) {
            int idx0 = REMSTART + 2*t;
            int idx1 = idx0 + 1;
            if (idx0 >= NS-256) r0 *= (1.0f - (float)(idx0-(NS-256))*(1.0f/255.0f));
            if (idx1 >= NS-256) r1 *= (1.0f - (float)(idx1-(NS-256))*(1.0f/255.0f));
            *(float2*)(out + idx0) = make_float2(r0, r1);
        }
    }
}

// ---------------- K4: BR pass 1 — zero-y-state chunk offsets ----------------
__global__ __launch_bounds__(256) void k4_br1(const float* __restrict__ x,
                                              const float* __restrict__ h,
                                              float* __restrict__ ws) {
    __shared__ float tile[256*33];
    const int tid = threadIdx.x;
    const int c = blockIdx.x*256 + tid;
    const long base = (long)blockIdx.x * (256*BRL);
    float B0,B1,B2,A1,A2;
    {
        float freq = clipf(h[5]*(SRF/4.0f), 100.0f, SRF/2.0f - 1.0f);
        float q = clipf(h[6], 0.1f, 0.999f);
        float w0 = TWO_PI * freq / SRF;
        float sw = sinf(w0), cw = cosf(w0);
        float alpha = sw / (2.0f * q);
        float a0 = 1.0f + alpha;
        B0 = 1.0f/a0; B1 = (-2.0f*cw)/a0; B2 = 1.0f/a0;
        A1 = (-2.0f*cw)/a0; A2 = (1.0f - alpha)/a0;
    }
    float x1, x2, y1=0.f, y2=0.f;
    {
        long g0 = (long)c * BRL;
        x1 = (c>0) ? x[g0-1] : 0.0f;
        x2 = (c>0) ? x[g0-2] : 0.0f;
    }
    for (int tt=0; tt<BRL/32; tt++) {
        const float4* src4 = (const float4*)(x + base + (long)tt*32);
        for (int q = tid; q < 256*8; q += 256) {
            int r = q >> 3, c4 = q & 7;
            float4 v = src4[(long)r*(BRL/4) + c4];
            tile[r*33 + c4*4 + 0] = v.x;
            tile[r*33 + c4*4 + 1] = v.y;
            tile[r*33 + c4*4 + 2] = v.z;
            tile[r*33 + c4*4 + 3] = v.w;
        }
        __syncthreads();
        #pragma unroll
        for (int j=0;j<32;j++){
            float xv = tile[tid*33 + j];
            float y = B0*xv + B1*x1 + B2*x2 - A1*y1 - A2*y2;
            x2=x1; x1=xv; y2=y1; y1=y;
        }
        __syncthreads();
    }
    ws[WS_BRD + 2*c]   = y1;
    ws[WS_BRD + 2*c+1] = y2;
    ws[WS_XT1 + c] = x1;
    ws[WS_XT2 + c] = x2;
}

// ---------------- KP: BR incoming states via truncated window (parallel) ----
__global__ __launch_bounds__(256) void kP_state(const float* __restrict__ h,
                                                float* __restrict__ ws) {
    __shared__ float sld[2*(256+WDEPTH)];
    const int tid = threadIdx.x;
    const int bid = blockIdx.x;
    float A1,A2;
    {
        float freq = clipf(h[5]*(SRF/4.0f), 100.0f, SRF/2.0f - 1.0f);
        float q = clipf(h[6], 0.1f, 0.999f);
        float w0 = TWO_PI * freq / SRF;
        float sw = sinf(w0), cw = cosf(w0);
        float alpha = sw / (2.0f * q);
        float a0 = 1.0f + alpha;
        A1 = (-2.0f*cw)/a0; A2 = (1.0f - alpha)/a0;
    }
    // T = A^128 (7 squarings, double)
    double t00=-A1, t01=-A2, t10=1.0, t11=0.0;
    for (int k=0;k<7;k++){
        double na=t00*t00+t01*t10, nb=t00*t01+t01*t11;
        double nc=t10*t00+t11*t10, nd=t10*t01+t11*t11;
        t00=na;t01=nb;t10=nc;t11=nd;
    }
    const float T00=(float)t00, T01=(float)t01, T10=(float)t10, T11=(float)t11;
    const int base = bid*256 - WDEPTH;
    for (int j = tid; j < 256+WDEPTH; j += 256) {
        int r = base + j;
        float a=0.f, b=0.f;
        if (r >= 0) { a = ws[WS_BRD + 2*r]; b = ws[WS_BRD + 2*r + 1]; }
        sld[2*j] = a; sld[2*j+1] = b;
    }
    __syncthreads();
    const int li = tid + WDEPTH;
    float e1 = sld[2*(li-1)], e2 = sld[2*(li-1)+1];
    float P00=T00,P01=T01,P10=T10,P11=T11;
    #pragma unroll 4
    for (int u = 1; u < WDEPTH; u++) {
        float d1 = sld[2*(li-1-u)], d2_ = sld[2*(li-1-u)+1];
        e1 = fmaf(P00,d1, fmaf(P01,d2_, e1));
        e2 = fmaf(P10,d1, fmaf(P11,d2_, e2));
        float n00 = P00*T00+P01*T10, n01 = P00*T01+P01*T11;
        float n10 = P10*T00+P11*T10, n11 = P10*T01+P11*T11;
        P00=n00;P01=n01;P10=n10;P11=n11;
    }
    const int c = bid*256 + tid;
    ws[WS_BRS + 2*c]   = e1;
    ws[WS_BRS + 2*c+1] = e2;
}

// ---------------- K6: BR pass 3 — true outputs + envelope, in-place ---------
__global__ __launch_bounds__(256) void k6_br2(float* __restrict__ x,
                                              const float* __restrict__ h,
                                              const float* __restrict__ envp,
                                              const float* __restrict__ ws) {
    __shared__ float tile[256*33];
    const int tid = threadIdx.x;
    const int c = blockIdx.x*256 + tid;
    const long base = (long)blockIdx.x * (256*BRL);
    float B0,B1,B2,A1,A2;
    {
        float freq = clipf(h[5]*(SRF/4.0f), 100.0f, SRF/2.0f - 1.0f);
        float q = clipf(h[6], 0.1f, 0.999f);
        float w0 = TWO_PI * freq / SRF;
        float sw = sinf(w0), cw = cosf(w0);
        float alpha = sw / (2.0f * q);
        float a0 = 1.0f + alpha;
        B0 = 1.0f/a0; B1 = (-2.0f*cw)/a0; B2 = 1.0f/a0;
        A1 = (-2.0f*cw)/a0; A2 = (1.0f - alpha)/a0;
    }
    const float nF = (float)NS;
    const float invA = 1.0f/(1.0f + envp[0]*0.1f*nF);
    const float invR = 1.0f/(1.0f + envp[2]*0.1f*nF);
    const float sa_ = clipf(envp[1], 0.0f, 1.0f) * h[4];
    float x1 = (c>0)? ws[WS_XT1 + c-1] : 0.0f;
    float x2 = (c>0)? ws[WS_XT2 + c-1] : 0.0f;
    float y1 = ws[WS_BRS + 2*c];
    float y2 = ws[WS_BRS + 2*c+1];
    for (int tt=0; tt<BRL/32; tt++) {
        float4* dst4 = (float4*)(x + base + (long)tt*32);
        for (int q = tid; q < 256*8; q += 256) {
            int r = q >> 3, c4 = q & 7;
            float4 v = ((const float4*)dst4)[(long)r*(BRL/4) + c4];
            tile[r*33 + c4*4 + 0] = v.x;
            tile[r*33 + c4*4 + 1] = v.y;
            tile[r*33 + c4*4 + 2] = v.z;
            tile[r*33 + c4*4 + 3] = v.w;
        }
        __syncthreads();
        #pragma unroll
        for (int j=0;j<32;j++){
            float xv = tile[tid*33 + j];
            float y = B0*xv + B1*x1 + B2*x2 - A1*y1 - A2*y2;
            x2=x1; x1=xv; y2=y1; y1=y;
            int idx = c*BRL + tt*32 + j;
            float ea = fminf((float)idx * invA, 1.0f);
            float er = fminf((float)(NS-1-idx) * invR, 1.0f);
            tile[tid*33 + j] = y * (ea*er*sa_);
        }
        __syncthreads();
        for (int q = tid; q < 256*8; q += 256) {
            int r = q >> 3, c4 = q & 7;
            float4 v;
            v.x = tile[r*33 + c4*4 + 0];
            v.y = tile[r*33 + c4*4 + 1];
            v.z = tile[r*33 + c4*4 + 2];
            v.w = tile[r*33 + c4*4 + 3];
            dst4[(long)r*(BRL/4) + c4] = v;
        }
        __syncthreads();
    }
}

extern "C" void kernel_launch(void* const* d_in, const int* in_sizes, int n_in,
                              void* d_out, int out_size, void* d_ws, size_t ws_size,
                              hipStream_t stream) {
    const float* fb   = (const float*)d_in[0];
    const float* wt   = (const float*)d_in[1];
    const float* h    = (const float*)d_in[2];
    const float* envp = (const float*)d_in[3];
    const float* lp2c = (const float*)d_in[4];
    float* out = (float*)d_out;
    float* ws  = (float*)d_ws;

    hipLaunchKernelGGL(k1_ksA,   dim3(G_CH+1), dim3(448), 0, stream, fb, wt, h, lp2c, ws);
    hipLaunchKernelGGL(kB_scan,  dim3(7),      dim3(64),  0, stream, h, ws);
    hipLaunchKernelGGL(k3_ksC,   dim3(G_CH),   dim3(448), 0, stream, fb, h, ws, out);
    hipLaunchKernelGGL(k4_br1,   dim3(256),    dim3(256), 0, stream, out, h, ws);
    hipLaunchKernelGGL(kP_state, dim3(256),    dim3(256), 0, stream, h, ws);
    hipLaunchKernelGGL(k6_br2,   dim3(256),    dim3(256), 0, stream, out, h, envp, ws);
}

// Round 9
// 218.143 us; speedup vs baseline: 2.2525x; 1.0613x over previous
//
#include <hip/hip_runtime.h>
#include <math.h>

#define SRF 44100.0f
#define TWO_PI 6.283185307179586f
#define W 882
#define NHALF 441
#define NFREQ 442
#define MCH 30
#define G_CH 317
#define NS 8388608
#define REMSTART 8387820
#define REMN 788
#define BRL 128
#define BRC 65536
#define WDEPTH 32
#define HALO 31
#define OWNW 126
#define NPOS 157

// ---- ws float layout ----
#define WS_CH   1024                   // 317*884 -> ends 281252
#define WS_DH   281344                 // 317*884 -> ends 561572
#define WS_CH0  561600                 // 884 -> ends 562484
// BR arrays reuse low region (KS finished before BR starts); DH dead after kB
#define WS_BRD  1024                   // 2*BRC
#define WS_BRS  (WS_BRD + 2*BRC)       // 2*BRC
#define WS_XT1  (WS_BRS + 2*BRC)       // BRC
#define WS_XT2  (WS_XT1 + BRC)         // BRC -> ends 394240

__device__ __forceinline__ float clipf(float x, float lo, float hi) {
    return fminf(fmaxf(x, lo), hi);
}

// resolvent g_n of y_n = -a1 y_{n-1} - a2 y_{n-2}, g_0=1, g_1=-a1
__device__ float resolvent(float a1f, float a2f, int n) {
    double a1 = (double)a1f, a2 = (double)a2f;
    double disc = a1*a1 - 4.0*a2;
    double scale = a1*a1 + 4.0*fabs(a2) + 1e-30;
    if (disc > 1e-9*scale) {
        double sq = sqrt(disc);
        double p1 = 0.5*(-a1+sq), p2 = 0.5*(-a1-sq);
        int k = n+1;
        double t1 = pow(fabs(p1), (double)k); if (p1 < 0.0 && (k&1)) t1 = -t1;
        double t2 = pow(fabs(p2), (double)k); if (p2 < 0.0 && (k&1)) t2 = -t2;
        return (float)((t1 - t2)/sq);
    } else if (disc < -1e-9*scale) {
        double r = sqrt(a2);
        double ct = -a1/(2.0*r);
        ct = fmin(1.0, fmax(-1.0, ct));
        double th = acos(ct);
        double sth = sin(th);
        double rn = pow(r, (double)n);
        return (float)(rn * sin((double)(n+1)*th) / sth);
    } else {
        double p = -0.5*a1;
        double t = pow(fabs(p), (double)n); if (p < 0.0 && (n&1)) t = -t;
        return (float)((double)(n+1)*t);
    }
}

// ---------------- kD: blocks 0..316 = KS zero-state deltas (barrier-free halo)
// ----------------     block 317 = wavetable cascade; both end with 4-way DFT
__global__ __launch_bounds__(448) void kD_ksA(const float* __restrict__ fb,
                                              const float* __restrict__ wt,
                                              const float* __restrict__ h,
                                              const float* __restrict__ lp2c,
                                              float* __restrict__ ws) {
    __shared__ float sv[W];
    __shared__ __align__(16) float se[444];
    __shared__ __align__(16) float so[444];
    __shared__ float sx[W], sg[W], su[W], sy2[W];
    const int t = threadIdx.x;
    const int g = blockIdx.x;

    if (g == G_CH) {
        float b10,b11,b12,a11,a12, b20,b21,b22,a21,a22;
        {
            float freq = clipf(h[1] * (SRF/4.0f), 100.0f, SRF/2.0f - 1.0f);
            float q    = clipf(h[2], 0.1f, 0.999f);
            float w0 = TWO_PI * freq / SRF;
            float sw = sinf(w0), cw = cosf(w0);
            float alpha = sw / (2.0f * q);
            float b0 = (1.0f - cw) * 0.5f, b1 = 1.0f - cw, b2 = b0;
            float a0 = 1.0f + alpha, a1 = -2.0f * cw, a2 = 1.0f - alpha;
            b10=b0/a0; b11=b1/a0; b12=b2/a0; a11=a1/a0; a12=a2/a0;
        }
        {
            float freq = 100.0f + lp2c[0]*8000.0f;
            float q = 0.707f;
            float w0 = TWO_PI * freq / SRF;
            float sw = sinf(w0), cw = cosf(w0);
            float alpha = sw / (2.0f * q);
            float b0 = (1.0f - cw) * 0.5f, b1 = 1.0f - cw, b2 = b0;
            float a0 = 1.0f + alpha, a1 = -2.0f * cw, a2 = 1.0f - alpha;
            b20=b0/a0; b21=b1/a0; b22=b2/a0; a21=a1/a0; a22=a2/a0;
        }
        const int i0 = t, i1 = W-1-t;   // balanced pairing: i0+i1 work = const
        if (t < NHALF) {
            sx[i0]=wt[i0]; sx[i1]=wt[i1];
            sg[i0]=resolvent(a11,a12,i0); sg[i1]=resolvent(a11,a12,i1);
        }
        __syncthreads();
        if (t < NHALF) {
            float acc=0.f; for (int k=0;k<=i0;k++) acc += sg[k]*sx[i0-k]; su[i0]=acc;
            acc=0.f;       for (int k=0;k<=i1;k++) acc += sg[k]*sx[i1-k]; su[i1]=acc;
        }
        __syncthreads();
        if (t < NHALF) {
            float y = b10*su[i0]; if (i0>=1) y+=b11*su[i0-1]; if (i0>=2) y+=b12*su[i0-2];
            sy2[i0]=y;
            y = b10*su[i1] + b11*su[i1-1] + b12*su[i1-2];
            sy2[i1]=y;
        }
        __syncthreads();
        if (t < NHALF) { sg[i0]=resolvent(a21,a22,i0); sg[i1]=resolvent(a21,a22,i1); }
        __syncthreads();
        if (t < NHALF) {
            float acc=0.f; for (int k=0;k<=i0;k++) acc += sg[k]*sy2[i0-k]; su[i0]=acc;
            acc=0.f;       for (int k=0;k<=i1;k++) acc += sg[k]*sy2[i1-k]; su[i1]=acc;
        }
        __syncthreads();
        if (t < NHALF) {
            float y = b20*su[i0]; if (i0>=1) y+=b21*su[i0-1]; if (i0>=2) y+=b22*su[i0-2];
            sv[i0]=y;
            y = b20*su[i1] + b21*su[i1-1] + b22*su[i1-2];
            sv[i1]=y;
        }
    } else {
        const float decay = clipf(h[0]/10.0f + 0.9f, 0.9f, 0.999f);
        const float d2 = decay*0.5f;
        const float fa = h[3];
        const int lane = t & 63, wv = t >> 6;
        const int q0 = 3*lane;
        const int bp = OWNW*wv - HALO;
        const bool va0 = (q0   < NPOS), va1 = (q0+1 < NPOS), va2 = (q0+2 < NPOS);
        int p0 = bp + q0, p1 = p0+1, p2 = p0+2;
        int pw0 = va0 ? (p0<0 ? p0+W : p0) : 0;
        int pw1 = va1 ? (p1<0 ? p1+W : p1) : 0;
        int pw2 = va2 ? (p2<0 ? p2+W : p2) : 0;
        const float* fbg = fb + (long)g*(MCH*W);
        float z0=0.f, z1=0.f, z2=0.f;
        float c0 = fbg[pw0], c1 = fbg[pw1], c2v = fbg[pw2];
        for (int j=0;j<MCH;j++){
            float n0=0.f,n1=0.f,n2=0.f;
            if (j+1<MCH){ const float* fj = fbg + (j+1)*W; n0=fj[pw0]; n1=fj[pw1]; n2=fj[pw2]; }
            float v0 = z0 + tanhf(fa*c0);
            float v1 = z1 + tanhf(fa*c1);
            float v2 = z2 + tanhf(fa*c2v);
            float vp = __shfl_up(v2, 1);
            z0 = d2*(v0+vp); z1 = d2*(v1+v0); z2 = d2*(v2+v1);
            c0=n0; c1=n1; c2v=n2;
        }
        if (va0 && q0   >= HALO) sv[p0] = z0;
        if (va1 && q0+1 >= HALO) sv[p1] = z1;
        if (va2 && q0+2 >= HALO) sv[p2] = z2;
    }
    __syncthreads();
    if (t < NHALF) { se[t] = sv[t]+sv[t+NHALF]; so[t] = sv[t]-sv[t+NHALF]; }
    __syncthreads();
    if (t < NFREQ) {
        const int f = t;
        const float phf = (float)f * (TWO_PI/(float)W);
        float s1v, c1v; __sincosf(phf, &s1v, &c1v);
        float s4v, c4v; __sincosf(4.0f*phf, &s4v, &c4v);
        const float* yb = (f & 1) ? so : se;
        float a0r=0.f,a0i=0.f,a1r=0.f,a1i=0.f,a2r=0.f,a2i=0.f,a3r=0.f,a3i=0.f;
        float rr=1.0f, ri=0.0f;                  // e^{-i*4*phf*m}
        for (int m=0;m<110;m++){
            float4 y = *((const float4*)yb + m);
            a0r = fmaf(y.x, rr, a0r); a0i = fmaf(y.x, ri, a0i);
            a1r = fmaf(y.y, rr, a1r); a1i = fmaf(y.y, ri, a1i);
            a2r = fmaf(y.z, rr, a2r); a2i = fmaf(y.z, ri, a2i);
            a3r = fmaf(y.w, rr, a3r); a3i = fmaf(y.w, ri, a3i);
            float tr = rr;
            rr = fmaf(tr, c4v,  ri*s4v);
            ri = fmaf(ri, c4v, -tr*s4v);
        }
        a0r = fmaf(yb[440], rr, a0r); a0i = fmaf(yb[440], ri, a0i);  // tail k=440
        float w1r = c1v,  w1i = -s1v;            // e^{-i phf}
        float w2r = c1v*c1v - s1v*s1v;
        float w2i = -2.0f*c1v*s1v;
        float w3r = w1r*w2r - w1i*w2i;
        float w3i = w1r*w2i + w1i*w2r;
        float Xr = a0r + w1r*a1r - w1i*a1i + w2r*a2r - w2i*a2i + w3r*a3r - w3i*a3i;
        float Xi = a0i + w1r*a1i + w1i*a1r + w2r*a2i + w2i*a2r + w3r*a3i + w3i*a3r;
        float2* dst = (float2*)(ws + ((g==G_CH) ? (long)WS_CH0 : (long)WS_DH + (long)g*(2*NFREQ)));
        dst[f] = make_float2(Xr, Xi);
    }
}

// ---------------- kB: per-frequency scan over chunks (8-deep pipeline) ------
__global__ __launch_bounds__(64) void kB_scan(const float* __restrict__ h,
                                              float* __restrict__ ws) {
    const int f = blockIdx.x*64 + threadIdx.x;
    if (f >= NFREQ) return;
    const float decay = clipf(h[0] / 10.0f + 0.9f, 0.9f, 0.999f);
    const float d2 = decay * 0.5f;
    double phi = (double)f * (double)(TWO_PI) / (double)W;
    double m2 = 2.0 * (double)d2 * cos(0.5*phi);
    double mag = pow(m2, (double)MCH);
    double ang = -0.5 * (double)MCH * phi;
    float mre = (float)(mag * cos(ang));
    float mim = (float)(mag * sin(ang));
    float cre = ws[WS_CH0 + 2*f];
    float cim = ws[WS_CH0 + 2*f+1];
    float* CH = ws + WS_CH;
    const float* DH = ws + WS_DH;
    CH[2*f] = cre; CH[2*f+1] = cim;
    float cr8[8], ci8[8], nr8[8], ni8[8];
    #pragma unroll
    for (int u = 0; u < 8; u++) {
        cr8[u] = DH[(long)u*(2*NFREQ) + 2*f];
        ci8[u] = DH[(long)u*(2*NFREQ) + 2*f+1];
    }
    for (int b = 0; b < 39; b++) {
        const int gnext = 1 + (b+1)*8;
        if (b < 38) {
            #pragma unroll
            for (int u = 0; u < 8; u++) {
                nr8[u] = DH[(long)(gnext-1+u)*(2*NFREQ) + 2*f];
                ni8[u] = DH[(long)(gnext-1+u)*(2*NFREQ) + 2*f+1];
            }
        } else {
            #pragma unroll
            for (int u = 0; u < 4; u++) {
                nr8[u] = DH[(long)(gnext-1+u)*(2*NFREQ) + 2*f];
                ni8[u] = DH[(long)(gnext-1+u)*(2*NFREQ) + 2*f+1];
            }
        }
        const int g0 = 1 + b*8;
        #pragma unroll
        for (int u = 0; u < 8; u++) {
            float nre = mre*cre - mim*cim + cr8[u];
            float nim = mre*cim + mim*cre + ci8[u];
            cre = nre; cim = nim;
            CH[(long)(g0+u)*(2*NFREQ) + 2*f]   = cre;
            CH[(long)(g0+u)*(2*NFREQ) + 2*f+1] = cim;
        }
        #pragma unroll
        for (int u = 0; u < 8; u++) { cr8[u] = nr8[u]; ci8[u] = ni8[u]; }
    }
    #pragma unroll
    for (int u = 0; u < 4; u++) {
        float nre = mre*cre - mim*cim + cr8[u];
        float nim = mre*cim + mim*cre + ci8[u];
        cre = nre; cim = nim;
        CH[(long)(313+u)*(2*NFREQ) + 2*f]   = cre;
        CH[(long)(313+u)*(2*NFREQ) + 2*f+1] = cim;
    }
}

// ---------------- k3: IDFT + barrier-free halo time loop + outputs + fade ---
__global__ __launch_bounds__(448) void k3_ksC(const float* __restrict__ fb,
                                              const float* __restrict__ h,
                                              const float* __restrict__ ws,
                                              float* __restrict__ out) {
    __shared__ float chs[2*NFREQ];
    __shared__ float cini[W];
    const int t = threadIdx.x;
    const int g = blockIdx.x;
    const float decay = clipf(h[0]/10.0f + 0.9f, 0.9f, 0.999f);
    const float d2 = decay*0.5f;
    const float fa = h[3];
    if (t < NFREQ) {
        float2 v = ((const float2*)(ws + WS_CH + (long)g*(2*NFREQ)))[t];
        chs[2*t] = v.x; chs[2*t+1] = v.y;
    }
    __syncthreads();
    if (t < NHALF) {
        const int j = t;
        float aj = (float)j * (TWO_PI / (float)W);
        float sA, cA; __sincosf(aj, &sA, &cA);
        float s2, c2; __sincosf(2.0f*aj, &s2, &c2);
        float rr = 1.0f, ri = 0.0f;
        float RE = 0.0f, SOr = 0.0f, SOi = 0.0f;
        for (int m = 0; m < 220; m++) {
            float xr = chs[4*m+2], xi = chs[4*m+3];
            SOr = fmaf(xr, rr, SOr); SOr = fmaf(-xi, ri, SOr);
            SOi = fmaf(xr, ri, SOi); SOi = fmaf( xi, rr, SOi);
            float tr = rr;
            rr = fmaf(tr, c2, -ri*s2);
            ri = fmaf(ri, c2,  tr*s2);
            float yr = chs[4*m+4], yi = chs[4*m+5];
            RE = fmaf(yr, rr, RE); RE = fmaf(-yi, ri, RE);
        }
        float RO = cA*SOr - sA*SOi;
        float sgn = (j & 1) ? -1.0f : 1.0f;
        float base0 = chs[0] + sgn*chs[2*NHALF];
        float base1 = chs[0] - sgn*chs[2*NHALF];
        cini[j]        = (base0 + 2.0f*(RE + RO)) * (1.0f/(float)W);
        cini[j+NHALF]  = (base1 + 2.0f*(RE - RO)) * (1.0f/(float)W);
    }
    __syncthreads();
    const int lane = t & 63, wv = t >> 6;
    const int q0 = 3*lane;
    const int bp = OWNW*wv - HALO;
    const bool va0 = (q0   < NPOS), va1 = (q0+1 < NPOS), va2 = (q0+2 < NPOS);
    int p0 = bp + q0, p1 = p0+1, p2 = p0+2;
    int pw0 = va0 ? (p0<0 ? p0+W : p0) : 0;
    int pw1 = va1 ? (p1<0 ? p1+W : p1) : 0;
    int pw2 = va2 ? (p2<0 ? p2+W : p2) : 0;
    const bool ow0 = va0 && q0   >= HALO;
    const bool ow1 = va1 && q0+1 >= HALO;
    const bool ow2 = va2 && q0+2 >= HALO;
    float z0 = cini[pw0], z1 = cini[pw1], z2 = cini[pw2];
    const float* fbg = fb + (long)g*(MCH*W);
    float* outg = out + (long)g*(MCH*W);
    float c0 = fbg[pw0], c1 = fbg[pw1], c2v = fbg[pw2];
    for (int j=0;j<MCH;j++){
        float n0=0.f,n1=0.f,n2=0.f;
        if (j+1<MCH){ const float* fj = fbg + (j+1)*W; n0=fj[pw0]; n1=fj[pw1]; n2=fj[pw2]; }
        float v0 = z0 + tanhf(fa*c0);
        float v1 = z1 + tanhf(fa*c1);
        float v2 = z2 + tanhf(fa*c2v);
        float vp = __shfl_up(v2, 1);
        z0 = d2*(v0+vp); z1 = d2*(v1+v0); z2 = d2*(v2+v1);
        float* oj = outg + (long)j*W;
        if (ow0) oj[p0] = z0;
        if (ow1) oj[p1] = z1;
        if (ow2) oj[p2] = z2;
        c0=n0; c1=n1; c2v=n2;
    }
    if (g == G_CH-1) {
        // one decay step without feedback; write first 788, fade last 256
        float v0 = z0, v1 = z1, v2 = z2;
        float vp = __shfl_up(v2, 1);
        float r0 = d2*(v0+vp), r1 = d2*(v1+v0), r2 = d2*(v2+v1);
        if (ow0 && p0 < REMN) {
            int idx = REMSTART + p0; float r = r0;
            if (idx >= NS-256) r *= (1.0f - (float)(idx-(NS-256))*(1.0f/255.0f));
            out[idx] = r;
        }
        if (ow1 && p1 < REMN) {
            int idx = REMSTART + p1; float r = r1;
            if (idx >= NS-256) r *= (1.0f - (float)(idx-(NS-256))*(1.0f/255.0f));
            out[idx] = r;
        }
        if (ow2 && p2 < REMN) {
            int idx = REMSTART + p2; float r = r2;
            if (idx >= NS-256) r *= (1.0f - (float)(idx-(NS-256))*(1.0f/255.0f));
            out[idx] = r;
        }
    }
}

// ---------------- k4: BR pass 1 — zero-y-state chunk offsets ----------------
__global__ __launch_bounds__(256) void k4_br1(const float* __restrict__ x,
                                              const float* __restrict__ h,
                                              float* __restrict__ ws) {
    __shared__ float tile[256*33];
    const int tid = threadIdx.x;
    const int c = blockIdx.x*256 + tid;
    const long base = (long)blockIdx.x * (256*BRL);
    float B0,B1,B2,A1,A2;
    {
        float freq = clipf(h[5]*(SRF/4.0f), 100.0f, SRF/2.0f - 1.0f);
        float q = clipf(h[6], 0.1f, 0.999f);
        float w0 = TWO_PI * freq / SRF;
        float sw = sinf(w0), cw = cosf(w0);
        float alpha = sw / (2.0f * q);
        float a0 = 1.0f + alpha;
        B0 = 1.0f/a0; B1 = (-2.0f*cw)/a0; B2 = 1.0f/a0;
        A1 = (-2.0f*cw)/a0; A2 = (1.0f - alpha)/a0;
    }
    float x1, x2, y1=0.f, y2=0.f;
    {
        long g0 = (long)c * BRL;
        x1 = (c>0) ? x[g0-1] : 0.0f;
        x2 = (c>0) ? x[g0-2] : 0.0f;
    }
    for (int tt=0; tt<BRL/32; tt++) {
        const float4* src4 = (const float4*)(x + base + (long)tt*32);
        for (int q = tid; q < 256*8; q += 256) {
            int r = q >> 3, c4 = q & 7;
            float4 v = src4[(long)r*(BRL/4) + c4];
            tile[r*33 + c4*4 + 0] = v.x;
            tile[r*33 + c4*4 + 1] = v.y;
            tile[r*33 + c4*4 + 2] = v.z;
            tile[r*33 + c4*4 + 3] = v.w;
        }
        __syncthreads();
        #pragma unroll
        for (int j=0;j<32;j++){
            float xv = tile[tid*33 + j];
            float y = B0*xv + B1*x1 + B2*x2 - A1*y1 - A2*y2;
            x2=x1; x1=xv; y2=y1; y1=y;
        }
        __syncthreads();
    }
    ws[WS_BRD + 2*c]   = y1;
    ws[WS_BRD + 2*c+1] = y2;
    ws[WS_XT1 + c] = x1;
    ws[WS_XT2 + c] = x2;
}

// ---------------- kP: BR incoming states via truncated window (parallel) ----
__global__ __launch_bounds__(256) void kP_state(const float* __restrict__ h,
                                                float* __restrict__ ws) {
    __shared__ float sld[2*(256+WDEPTH)];
    const int tid = threadIdx.x;
    const int bid = blockIdx.x;
    float A1,A2;
    {
        float freq = clipf(h[5]*(SRF/4.0f), 100.0f, SRF/2.0f - 1.0f);
        float q = clipf(h[6], 0.1f, 0.999f);
        float w0 = TWO_PI * freq / SRF;
        float sw = sinf(w0), cw = cosf(w0);
        float alpha = sw / (2.0f * q);
        float a0 = 1.0f + alpha;
        A1 = (-2.0f*cw)/a0; A2 = (1.0f - alpha)/a0;
    }
    double t00=-A1, t01=-A2, t10=1.0, t11=0.0;
    for (int k=0;k<7;k++){
        double na=t00*t00+t01*t10, nb=t00*t01+t01*t11;
        double nc=t10*t00+t11*t10, nd=t10*t01+t11*t11;
        t00=na;t01=nb;t10=nc;t11=nd;
    }
    const float T00=(float)t00, T01=(float)t01, T10=(float)t10, T11=(float)t11;
    const int base = bid*256 - WDEPTH;
    for (int j = tid; j < 256+WDEPTH; j += 256) {
        int r = base + j;
        float a=0.f, b=0.f;
        if (r >= 0) { a = ws[WS_BRD + 2*r]; b = ws[WS_BRD + 2*r + 1]; }
        sld[2*j] = a; sld[2*j+1] = b;
    }
    __syncthreads();
    const int li = tid + WDEPTH;
    float e1 = sld[2*(li-1)], e2 = sld[2*(li-1)+1];
    float P00=T00,P01=T01,P10=T10,P11=T11;
    #pragma unroll 4
    for (int u = 1; u < WDEPTH; u++) {
        float d1 = sld[2*(li-1-u)], d2_ = sld[2*(li-1-u)+1];
        e1 = fmaf(P00,d1, fmaf(P01,d2_, e1));
        e2 = fmaf(P10,d1, fmaf(P11,d2_, e2));
        float n00 = P00*T00+P01*T10, n01 = P00*T01+P01*T11;
        float n10 = P10*T00+P11*T10, n11 = P10*T01+P11*T11;
        P00=n00;P01=n01;P10=n10;P11=n11;
    }
    const int c = bid*256 + tid;
    ws[WS_BRS + 2*c]   = e1;
    ws[WS_BRS + 2*c+1] = e2;
}

// ---------------- k6: BR pass 3 — true outputs + envelope, in-place ---------
__global__ __launch_bounds__(256) void k6_br2(float* __restrict__ x,
                                              const float* __restrict__ h,
                                              const float* __restrict__ envp,
                                              const float* __restrict__ ws) {
    __shared__ float tile[256*33];
    const int tid = threadIdx.x;
    const int c = blockIdx.x*256 + tid;
    const long base = (long)blockIdx.x * (256*BRL);
    float B0,B1,B2,A1,A2;
    {
        float freq = clipf(h[5]*(SRF/4.0f), 100.0f, SRF/2.0f - 1.0f);
        float q = clipf(h[6], 0.1f, 0.999f);
        float w0 = TWO_PI * freq / SRF;
        float sw = sinf(w0), cw = cosf(w0);
        float alpha = sw / (2.0f * q);
        float a0 = 1.0f + alpha;
        B0 = 1.0f/a0; B1 = (-2.0f*cw)/a0; B2 = 1.0f/a0;
        A1 = (-2.0f*cw)/a0; A2 = (1.0f - alpha)/a0;
    }
    const float nF = (float)NS;
    const float invA = 1.0f/(1.0f + envp[0]*0.1f*nF);
    const float invR = 1.0f/(1.0f + envp[2]*0.1f*nF);
    const float sa_ = clipf(envp[1], 0.0f, 1.0f) * h[4];
    float x1 = (c>0)? ws[WS_XT1 + c-1] : 0.0f;
    float x2 = (c>0)? ws[WS_XT2 + c-1] : 0.0f;
    float y1 = ws[WS_BRS + 2*c];
    float y2 = ws[WS_BRS + 2*c+1];
    for (int tt=0; tt<BRL/32; tt++) {
        float4* dst4 = (float4*)(x + base + (long)tt*32);
        for (int q = tid; q < 256*8; q += 256) {
            int r = q >> 3, c4 = q & 7;
            float4 v = ((const float4*)dst4)[(long)r*(BRL/4) + c4];
            tile[r*33 + c4*4 + 0] = v.x;
            tile[r*33 + c4*4 + 1] = v.y;
            tile[r*33 + c4*4 + 2] = v.z;
            tile[r*33 + c4*4 + 3] = v.w;
        }
        __syncthreads();
        #pragma unroll
        for (int j=0;j<32;j++){
            float xv = tile[tid*33 + j];
            float y = B0*xv + B1*x1 + B2*x2 - A1*y1 - A2*y2;
            x2=x1; x1=xv; y2=y1; y1=y;
            int idx = c*BRL + tt*32 + j;
            float ea = fminf((float)idx * invA, 1.0f);
            float er = fminf((float)(NS-1-idx) * invR, 1.0f);
            tile[tid*33 + j] = y * (ea*er*sa_);
        }
        __syncthreads();
        for (int q = tid; q < 256*8; q += 256) {
            int r = q >> 3, c4 = q & 7;
            float4 v;
            v.x = tile[r*33 + c4*4 + 0];
            v.y = tile[r*33 + c4*4 + 1];
            v.z = tile[r*33 + c4*4 + 2];
            v.w = tile[r*33 + c4*4 + 3];
            dst4[(long)r*(BRL/4) + c4] = v;
        }
        __syncthreads();
    }
}

extern "C" void kernel_launch(void* const* d_in, const int* in_sizes, int n_in,
                              void* d_out, int out_size, void* d_ws, size_t ws_size,
                              hipStream_t stream) {
    const float* fb   = (const float*)d_in[0];
    const float* wt   = (const float*)d_in[1];
    const float* h    = (const float*)d_in[2];
    const float* envp = (const float*)d_in[3];
    const float* lp2c = (const float*)d_in[4];
    float* out = (float*)d_out;
    float* ws  = (float*)d_ws;

    hipLaunchKernelGGL(kD_ksA,   dim3(G_CH+1), dim3(448), 0, stream, fb, wt, h, lp2c, ws);
    hipLaunchKernelGGL(kB_scan,  dim3(7),      dim3(64),  0, stream, h, ws);
    hipLaunchKernelGGL(k3_ksC,   dim3(G_CH),   dim3(448), 0, stream, fb, h, ws, out);
    hipLaunchKernelGGL(k4_br1,   dim3(256),    dim3(256), 0, stream, out, h, ws);
    hipLaunchKernelGGL(kP_state, dim3(256),    dim3(256), 0, stream, h, ws);
    hipLaunchKernelGGL(k6_br2,   dim3(256),    dim3(256), 0, stream, out, h, envp, ws);
}

// Round 10
// 216.648 us; speedup vs baseline: 2.2681x; 1.0069x over previous
//
#include <hip/hip_runtime.h>
#include <math.h>

#define SRF 44100.0f
#define TWO_PI 6.283185307179586f
#define W 882
#define NHALF 441
#define NFREQ 442
#define MCH 30
#define G_CH 317
#define NS 8388608
#define REMSTART 8387820
#define REMN 788
#define BRL 128
#define BRC 65536
#define WDEPTH 32
#define HALO 31
#define OWNW 126
#define NPOS 157
#define PD 10

// ---- ws float layout ----
#define WS_CH   1024                   // 317*884 -> ends 281252
#define WS_DH   281344                 // 317*884 -> ends 561572
#define WS_CH0  561600                 // 884 -> ends 562484
// BR arrays reuse low region (KS finished before BR starts); DH dead after kB
#define WS_BRD  1024                   // 2*BRC
#define WS_BRS  (WS_BRD + 2*BRC)       // 2*BRC
#define WS_XT1  (WS_BRS + 2*BRC)       // BRC
#define WS_XT2  (WS_XT1 + BRC)         // BRC -> ends 394240

__device__ __forceinline__ float clipf(float x, float lo, float hi) {
    return fminf(fmaxf(x, lo), hi);
}

// fast tanh: 1 - 2/(e^{2x}+1); exact at saturation, ~1e-6 abs error
__device__ __forceinline__ float ftanh(float x) {
    float e = __expf(2.0f*x);
    return fmaf(-2.0f, __builtin_amdgcn_rcpf(e + 1.0f), 1.0f);
}

// resolvent g_n of y_n = -a1 y_{n-1} - a2 y_{n-2}, g_0=1, g_1=-a1
__device__ float resolvent(float a1f, float a2f, int n) {
    double a1 = (double)a1f, a2 = (double)a2f;
    double disc = a1*a1 - 4.0*a2;
    double scale = a1*a1 + 4.0*fabs(a2) + 1e-30;
    if (disc > 1e-9*scale) {
        double sq = sqrt(disc);
        double p1 = 0.5*(-a1+sq), p2 = 0.5*(-a1-sq);
        int k = n+1;
        double t1 = pow(fabs(p1), (double)k); if (p1 < 0.0 && (k&1)) t1 = -t1;
        double t2 = pow(fabs(p2), (double)k); if (p2 < 0.0 && (k&1)) t2 = -t2;
        return (float)((t1 - t2)/sq);
    } else if (disc < -1e-9*scale) {
        double r = sqrt(a2);
        double ct = -a1/(2.0*r);
        ct = fmin(1.0, fmax(-1.0, ct));
        double th = acos(ct);
        double sth = sin(th);
        double rn = pow(r, (double)n);
        return (float)(rn * sin((double)(n+1)*th) / sth);
    } else {
        double p = -0.5*a1;
        double t = pow(fabs(p), (double)n); if (p < 0.0 && (n&1)) t = -t;
        return (float)((double)(n+1)*t);
    }
}

// ---------------- kD: blocks 0..316 = KS zero-state deltas (halo, pipelined)
// ----------------     block 317 = wavetable cascade; both end with 4-way DFT
__global__ __launch_bounds__(448) void kD_ksA(const float* __restrict__ fb,
                                              const float* __restrict__ wt,
                                              const float* __restrict__ h,
                                              const float* __restrict__ lp2c,
                                              float* __restrict__ ws) {
    __shared__ float sv[W];
    __shared__ __align__(16) float se[444];
    __shared__ __align__(16) float so[444];
    __shared__ float sx[W], sg[W], su[W], sy2[W];
    const int t = threadIdx.x;
    const int g = blockIdx.x;

    if (g == G_CH) {
        float b10,b11,b12,a11,a12, b20,b21,b22,a21,a22;
        {
            float freq = clipf(h[1] * (SRF/4.0f), 100.0f, SRF/2.0f - 1.0f);
            float q    = clipf(h[2], 0.1f, 0.999f);
            float w0 = TWO_PI * freq / SRF;
            float sw = sinf(w0), cw = cosf(w0);
            float alpha = sw / (2.0f * q);
            float b0 = (1.0f - cw) * 0.5f, b1 = 1.0f - cw, b2 = b0;
            float a0 = 1.0f + alpha, a1 = -2.0f * cw, a2 = 1.0f - alpha;
            b10=b0/a0; b11=b1/a0; b12=b2/a0; a11=a1/a0; a12=a2/a0;
        }
        {
            float freq = 100.0f + lp2c[0]*8000.0f;
            float q = 0.707f;
            float w0 = TWO_PI * freq / SRF;
            float sw = sinf(w0), cw = cosf(w0);
            float alpha = sw / (2.0f * q);
            float b0 = (1.0f - cw) * 0.5f, b1 = 1.0f - cw, b2 = b0;
            float a0 = 1.0f + alpha, a1 = -2.0f * cw, a2 = 1.0f - alpha;
            b20=b0/a0; b21=b1/a0; b22=b2/a0; a21=a1/a0; a22=a2/a0;
        }
        const int i0 = t, i1 = W-1-t;
        if (t < NHALF) {
            sx[i0]=wt[i0]; sx[i1]=wt[i1];
            sg[i0]=resolvent(a11,a12,i0); sg[i1]=resolvent(a11,a12,i1);
        }
        __syncthreads();
        if (t < NHALF) {
            float acc=0.f; for (int k=0;k<=i0;k++) acc += sg[k]*sx[i0-k]; su[i0]=acc;
            acc=0.f;       for (int k=0;k<=i1;k++) acc += sg[k]*sx[i1-k]; su[i1]=acc;
        }
        __syncthreads();
        if (t < NHALF) {
            float y = b10*su[i0]; if (i0>=1) y+=b11*su[i0-1]; if (i0>=2) y+=b12*su[i0-2];
            sy2[i0]=y;
            y = b10*su[i1] + b11*su[i1-1] + b12*su[i1-2];
            sy2[i1]=y;
        }
        __syncthreads();
        if (t < NHALF) { sg[i0]=resolvent(a21,a22,i0); sg[i1]=resolvent(a21,a22,i1); }
        __syncthreads();
        if (t < NHALF) {
            float acc=0.f; for (int k=0;k<=i0;k++) acc += sg[k]*sy2[i0-k]; su[i0]=acc;
            acc=0.f;       for (int k=0;k<=i1;k++) acc += sg[k]*sy2[i1-k]; su[i1]=acc;
        }
        __syncthreads();
        if (t < NHALF) {
            float y = b20*su[i0]; if (i0>=1) y+=b21*su[i0-1]; if (i0>=2) y+=b22*su[i0-2];
            sv[i0]=y;
            y = b20*su[i1] + b21*su[i1-1] + b22*su[i1-2];
            sv[i1]=y;
        }
    } else {
        const float decay = clipf(h[0]/10.0f + 0.9f, 0.9f, 0.999f);
        const float d2 = decay*0.5f;
        const float fa = h[3];
        const int lane = t & 63, wv = t >> 6;
        const int q0 = 3*lane;
        const int bp = OWNW*wv - HALO;
        const bool va0 = (q0   < NPOS), va1 = (q0+1 < NPOS), va2 = (q0+2 < NPOS);
        int p0 = bp + q0, p1 = p0+1, p2 = p0+2;
        int pw0 = va0 ? (p0<0 ? p0+W : p0) : 0;
        int pw1 = va1 ? (p1<0 ? p1+W : p1) : 0;
        int pw2 = va2 ? (p2<0 ? p2+W : p2) : 0;
        const float* fbg = fb + (long)g*(MCH*W);
        float l0[MCH], l1[MCH], l2[MCH];
        #pragma unroll
        for (int j=0;j<PD;j++){
            const float* fj = fbg + j*W;
            l0[j]=fj[pw0]; l1[j]=fj[pw1]; l2[j]=fj[pw2];
        }
        float z0=0.f, z1=0.f, z2=0.f;
        #pragma unroll
        for (int j=0;j<MCH;j++){
            if (j+PD < MCH) {
                const float* fj = fbg + (j+PD)*W;
                l0[j+PD]=fj[pw0]; l1[j+PD]=fj[pw1]; l2[j+PD]=fj[pw2];
            }
            float v0 = z0 + ftanh(fa*l0[j]);
            float v1 = z1 + ftanh(fa*l1[j]);
            float v2 = z2 + ftanh(fa*l2[j]);
            float vp = __shfl_up(v2, 1);
            z0 = d2*(v0+vp); z1 = d2*(v1+v0); z2 = d2*(v2+v1);
        }
        if (va0 && q0   >= HALO) sv[p0] = z0;
        if (va1 && q0+1 >= HALO) sv[p1] = z1;
        if (va2 && q0+2 >= HALO) sv[p2] = z2;
    }
    __syncthreads();
    if (t < NHALF) { se[t] = sv[t]+sv[t+NHALF]; so[t] = sv[t]-sv[t+NHALF]; }
    __syncthreads();
    if (t < NFREQ) {
        const int f = t;
        const float phf = (float)f * (TWO_PI/(float)W);
        float s1v, c1v; __sincosf(phf, &s1v, &c1v);
        float s4v, c4v; __sincosf(4.0f*phf, &s4v, &c4v);
        const float* yb = (f & 1) ? so : se;
        float a0r=0.f,a0i=0.f,a1r=0.f,a1i=0.f,a2r=0.f,a2i=0.f,a3r=0.f,a3i=0.f;
        float rr=1.0f, ri=0.0f;                  // e^{-i*4*phf*m}
        for (int m=0;m<110;m++){
            float4 y = *((const float4*)yb + m);
            a0r = fmaf(y.x, rr, a0r); a0i = fmaf(y.x, ri, a0i);
            a1r = fmaf(y.y, rr, a1r); a1i = fmaf(y.y, ri, a1i);
            a2r = fmaf(y.z, rr, a2r); a2i = fmaf(y.z, ri, a2i);
            a3r = fmaf(y.w, rr, a3r); a3i = fmaf(y.w, ri, a3i);
            float tr = rr;
            rr = fmaf(tr, c4v,  ri*s4v);
            ri = fmaf(ri, c4v, -tr*s4v);
        }
        a0r = fmaf(yb[440], rr, a0r); a0i = fmaf(yb[440], ri, a0i);  // tail k=440
        float w1r = c1v,  w1i = -s1v;            // e^{-i phf}
        float w2r = c1v*c1v - s1v*s1v;
        float w2i = -2.0f*c1v*s1v;
        float w3r = w1r*w2r - w1i*w2i;
        float w3i = w1r*w2i + w1i*w2r;
        float Xr = a0r + w1r*a1r - w1i*a1i + w2r*a2r - w2i*a2i + w3r*a3r - w3i*a3i;
        float Xi = a0i + w1r*a1i + w1i*a1r + w2r*a2i + w2i*a2r + w3r*a3i + w3i*a3r;
        float2* dst = (float2*)(ws + ((g==G_CH) ? (long)WS_CH0 : (long)WS_DH + (long)g*(2*NFREQ)));
        dst[f] = make_float2(Xr, Xi);
    }
}

// ---------------- kB: per-frequency scan over chunks (8-deep pipeline) ------
__global__ __launch_bounds__(64) void kB_scan(const float* __restrict__ h,
                                              float* __restrict__ ws) {
    const int f = blockIdx.x*64 + threadIdx.x;
    if (f >= NFREQ) return;
    const float decay = clipf(h[0] / 10.0f + 0.9f, 0.9f, 0.999f);
    const float d2 = decay * 0.5f;
    double phi = (double)f * (double)(TWO_PI) / (double)W;
    double m2 = 2.0 * (double)d2 * cos(0.5*phi);
    double mag = pow(m2, (double)MCH);
    double ang = -0.5 * (double)MCH * phi;
    float mre = (float)(mag * cos(ang));
    float mim = (float)(mag * sin(ang));
    float cre = ws[WS_CH0 + 2*f];
    float cim = ws[WS_CH0 + 2*f+1];
    float* CH = ws + WS_CH;
    const float* DH = ws + WS_DH;
    CH[2*f] = cre; CH[2*f+1] = cim;
    float cr8[8], ci8[8], nr8[8], ni8[8];
    #pragma unroll
    for (int u = 0; u < 8; u++) {
        cr8[u] = DH[(long)u*(2*NFREQ) + 2*f];
        ci8[u] = DH[(long)u*(2*NFREQ) + 2*f+1];
    }
    for (int b = 0; b < 39; b++) {
        const int gnext = 1 + (b+1)*8;
        if (b < 38) {
            #pragma unroll
            for (int u = 0; u < 8; u++) {
                nr8[u] = DH[(long)(gnext-1+u)*(2*NFREQ) + 2*f];
                ni8[u] = DH[(long)(gnext-1+u)*(2*NFREQ) + 2*f+1];
            }
        } else {
            #pragma unroll
            for (int u = 0; u < 4; u++) {
                nr8[u] = DH[(long)(gnext-1+u)*(2*NFREQ) + 2*f];
                ni8[u] = DH[(long)(gnext-1+u)*(2*NFREQ) + 2*f+1];
            }
        }
        const int g0 = 1 + b*8;
        #pragma unroll
        for (int u = 0; u < 8; u++) {
            float nre = mre*cre - mim*cim + cr8[u];
            float nim = mre*cim + mim*cre + ci8[u];
            cre = nre; cim = nim;
            CH[(long)(g0+u)*(2*NFREQ) + 2*f]   = cre;
            CH[(long)(g0+u)*(2*NFREQ) + 2*f+1] = cim;
        }
        #pragma unroll
        for (int u = 0; u < 8; u++) { cr8[u] = nr8[u]; ci8[u] = ni8[u]; }
    }
    #pragma unroll
    for (int u = 0; u < 4; u++) {
        float nre = mre*cre - mim*cim + cr8[u];
        float nim = mre*cim + mim*cre + ci8[u];
        cre = nre; cim = nim;
        CH[(long)(313+u)*(2*NFREQ) + 2*f]   = cre;
        CH[(long)(313+u)*(2*NFREQ) + 2*f+1] = cim;
    }
}

// ---------------- k3: IDFT (float4 LDS) + pipelined halo loop + outputs -----
__global__ __launch_bounds__(448) void k3_ksC(const float* __restrict__ fb,
                                              const float* __restrict__ h,
                                              const float* __restrict__ ws,
                                              float* __restrict__ out) {
    __shared__ __align__(16) float4 chv[220];   // (X_{2m+1}, X_{2m+2})
    __shared__ float ch0s, ch441s;
    __shared__ float cini[W];
    const int t = threadIdx.x;
    const int g = blockIdx.x;
    const float decay = clipf(h[0]/10.0f + 0.9f, 0.9f, 0.999f);
    const float d2 = decay*0.5f;
    const float fa = h[3];
    if (t < NFREQ) {
        float2 v = ((const float2*)(ws + WS_CH + (long)g*(2*NFREQ)))[t];
        if (t == 0) ch0s = v.x;
        else if (t == NHALF) ch441s = v.x;
        else {
            int m = (t-1) >> 1;
            if (t & 1) { chv[m].x = v.x; chv[m].y = v.y; }
            else       { chv[m].z = v.x; chv[m].w = v.y; }
        }
    }
    __syncthreads();
    if (t < NHALF) {
        const int j = t;
        float aj = (float)j * (TWO_PI / (float)W);
        float sA, cA; __sincosf(aj, &sA, &cA);
        float s2, c2; __sincosf(2.0f*aj, &s2, &c2);
        float rr = 1.0f, ri = 0.0f;
        float RE = 0.0f, SOr = 0.0f, SOi = 0.0f;
        for (int m = 0; m < 220; m++) {
            float4 X = chv[m];
            SOr = fmaf(X.x, rr, SOr); SOr = fmaf(-X.y, ri, SOr);
            SOi = fmaf(X.x, ri, SOi); SOi = fmaf( X.y, rr, SOi);
            float tr = rr;
            rr = fmaf(tr, c2, -ri*s2);
            ri = fmaf(ri, c2,  tr*s2);
            RE = fmaf(X.z, rr, RE); RE = fmaf(-X.w, ri, RE);
        }
        float RO = cA*SOr - sA*SOi;
        float sgn = (j & 1) ? -1.0f : 1.0f;
        float base0 = ch0s + sgn*ch441s;
        float base1 = ch0s - sgn*ch441s;
        cini[j]        = (base0 + 2.0f*(RE + RO)) * (1.0f/(float)W);
        cini[j+NHALF]  = (base1 + 2.0f*(RE - RO)) * (1.0f/(float)W);
    }
    __syncthreads();
    const int lane = t & 63, wv = t >> 6;
    const int q0 = 3*lane;
    const int bp = OWNW*wv - HALO;
    const bool va0 = (q0   < NPOS), va1 = (q0+1 < NPOS), va2 = (q0+2 < NPOS);
    int p0 = bp + q0, p1 = p0+1, p2 = p0+2;
    int pw0 = va0 ? (p0<0 ? p0+W : p0) : 0;
    int pw1 = va1 ? (p1<0 ? p1+W : p1) : 0;
    int pw2 = va2 ? (p2<0 ? p2+W : p2) : 0;
    const bool ow0 = va0 && q0   >= HALO;
    const bool ow1 = va1 && q0+1 >= HALO;
    const bool ow2 = va2 && q0+2 >= HALO;
    float z0 = cini[pw0], z1 = cini[pw1], z2 = cini[pw2];
    const float* fbg = fb + (long)g*(MCH*W);
    float* outg = out + (long)g*(MCH*W);
    float l0[MCH], l1[MCH], l2[MCH];
    #pragma unroll
    for (int j=0;j<PD;j++){
        const float* fj = fbg + j*W;
        l0[j]=fj[pw0]; l1[j]=fj[pw1]; l2[j]=fj[pw2];
    }
    #pragma unroll
    for (int j=0;j<MCH;j++){
        if (j+PD < MCH) {
            const float* fj = fbg + (j+PD)*W;
            l0[j+PD]=fj[pw0]; l1[j+PD]=fj[pw1]; l2[j+PD]=fj[pw2];
        }
        float v0 = z0 + ftanh(fa*l0[j]);
        float v1 = z1 + ftanh(fa*l1[j]);
        float v2 = z2 + ftanh(fa*l2[j]);
        float vp = __shfl_up(v2, 1);
        z0 = d2*(v0+vp); z1 = d2*(v1+v0); z2 = d2*(v2+v1);
        float* oj = outg + (long)j*W;
        if (ow0) oj[p0] = z0;
        if (ow1) oj[p1] = z1;
        if (ow2) oj[p2] = z2;
    }
    if (g == G_CH-1) {
        float v0 = z0, v1 = z1, v2 = z2;
        float vp = __shfl_up(v2, 1);
        float r0 = d2*(v0+vp), r1 = d2*(v1+v0), r2 = d2*(v2+v1);
        if (ow0 && p0 < REMN) {
            int idx = REMSTART + p0; float r = r0;
            if (idx >= NS-256) r *= (1.0f - (float)(idx-(NS-256))*(1.0f/255.0f));
            out[idx] = r;
        }
        if (ow1 && p1 < REMN) {
            int idx = REMSTART + p1; float r = r1;
            if (idx >= NS-256) r *= (1.0f - (float)(idx-(NS-256))*(1.0f/255.0f));
            out[idx] = r;
        }
        if (ow2 && p2 < REMN) {
            int idx = REMSTART + p2; float r = r2;
            if (idx >= NS-256) r *= (1.0f - (float)(idx-(NS-256))*(1.0f/255.0f));
            out[idx] = r;
        }
    }
}

// ---------------- k4: BR pass 1 — zero-y-state chunk offsets ----------------
__global__ __launch_bounds__(256) void k4_br1(const float* __restrict__ x,
                                              const float* __restrict__ h,
                                              float* __restrict__ ws) {
    __shared__ float tile[256*33];
    const int tid = threadIdx.x;
    const int c = blockIdx.x*256 + tid;
    const long base = (long)blockIdx.x * (256*BRL);
    float B0,B1,B2,A1,A2;
    {
        float freq = clipf(h[5]*(SRF/4.0f), 100.0f, SRF/2.0f - 1.0f);
        float q = clipf(h[6], 0.1f, 0.999f);
        float w0 = TWO_PI * freq / SRF;
        float sw = sinf(w0), cw = cosf(w0);
        float alpha = sw / (2.0f * q);
        float a0 = 1.0f + alpha;
        B0 = 1.0f/a0; B1 = (-2.0f*cw)/a0; B2 = 1.0f/a0;
        A1 = (-2.0f*cw)/a0; A2 = (1.0f - alpha)/a0;
    }
    float x1, x2, y1=0.f, y2=0.f;
    {
        long g0 = (long)c * BRL;
        x1 = (c>0) ? x[g0-1] : 0.0f;
        x2 = (c>0) ? x[g0-2] : 0.0f;
    }
    for (int tt=0; tt<BRL/32; tt++) {
        const float4* src4 = (const float4*)(x + base + (long)tt*32);
        for (int q = tid; q < 256*8; q += 256) {
            int r = q >> 3, c4 = q & 7;
            float4 v = src4[(long)r*(BRL/4) + c4];
            tile[r*33 + c4*4 + 0] = v.x;
            tile[r*33 + c4*4 + 1] = v.y;
            tile[r*33 + c4*4 + 2] = v.z;
            tile[r*33 + c4*4 + 3] = v.w;
        }
        __syncthreads();
        #pragma unroll
        for (int j=0;j<32;j++){
            float xv = tile[tid*33 + j];
            float y = B0*xv + B1*x1 + B2*x2 - A1*y1 - A2*y2;
            x2=x1; x1=xv; y2=y1; y1=y;
        }
        __syncthreads();
    }
    ws[WS_BRD + 2*c]   = y1;
    ws[WS_BRD + 2*c+1] = y2;
    ws[WS_XT1 + c] = x1;
    ws[WS_XT2 + c] = x2;
}

// ---------------- kP: BR incoming states via truncated window (parallel) ----
__global__ __launch_bounds__(256) void kP_state(const float* __restrict__ h,
                                                float* __restrict__ ws) {
    __shared__ float sld[2*(256+WDEPTH)];
    const int tid = threadIdx.x;
    const int bid = blockIdx.x;
    float A1,A2;
    {
        float freq = clipf(h[5]*(SRF/4.0f), 100.0f, SRF/2.0f - 1.0f);
        float q = clipf(h[6], 0.1f, 0.999f);
        float w0 = TWO_PI * freq / SRF;
        float sw = sinf(w0), cw = cosf(w0);
        float alpha = sw / (2.0f * q);
        float a0 = 1.0f + alpha;
        A1 = (-2.0f*cw)/a0; A2 = (1.0f - alpha)/a0;
    }
    double t00=-A1, t01=-A2, t10=1.0, t11=0.0;
    for (int k=0;k<7;k++){
        double na=t00*t00+t01*t10, nb=t00*t01+t01*t11;
        double nc=t10*t00+t11*t10, nd=t10*t01+t11*t11;
        t00=na;t01=nb;t10=nc;t11=nd;
    }
    const float T00=(float)t00, T01=(float)t01, T10=(float)t10, T11=(float)t11;
    const int base = bid*256 - WDEPTH;
    for (int j = tid; j < 256+WDEPTH; j += 256) {
        int r = base + j;
        float a=0.f, b=0.f;
        if (r >= 0) { a = ws[WS_BRD + 2*r]; b = ws[WS_BRD + 2*r + 1]; }
        sld[2*j] = a; sld[2*j+1] = b;
    }
    __syncthreads();
    const int li = tid + WDEPTH;
    float e1 = sld[2*(li-1)], e2 = sld[2*(li-1)+1];
    float P00=T00,P01=T01,P10=T10,P11=T11;
    #pragma unroll 4
    for (int u = 1; u < WDEPTH; u++) {
        float d1 = sld[2*(li-1-u)], d2_ = sld[2*(li-1-u)+1];
        e1 = fmaf(P00,d1, fmaf(P01,d2_, e1));
        e2 = fmaf(P10,d1, fmaf(P11,d2_, e2));
        float n00 = P00*T00+P01*T10, n01 = P00*T01+P01*T11;
        float n10 = P10*T00+P11*T10, n11 = P10*T01+P11*T11;
        P00=n00;P01=n01;P10=n10;P11=n11;
    }
    const int c = bid*256 + tid;
    ws[WS_BRS + 2*c]   = e1;
    ws[WS_BRS + 2*c+1] = e2;
}

// ---------------- k6: BR pass 3 — true outputs + envelope, in-place ---------
__global__ __launch_bounds__(256) void k6_br2(float* __restrict__ x,
                                              const float* __restrict__ h,
                                              const float* __restrict__ envp,
                                              const float* __restrict__ ws) {
    __shared__ float tile[256*33];
    const int tid = threadIdx.x;
    const int c = blockIdx.x*256 + tid;
    const long base = (long)blockIdx.x * (256*BRL);
    float B0,B1,B2,A1,A2;
    {
        float freq = clipf(h[5]*(SRF/4.0f), 100.0f, SRF/2.0f - 1.0f);
        float q = clipf(h[6], 0.1f, 0.999f);
        float w0 = TWO_PI * freq / SRF;
        float sw = sinf(w0), cw = cosf(w0);
        float alpha = sw / (2.0f * q);
        float a0 = 1.0f + alpha;
        B0 = 1.0f/a0; B1 = (-2.0f*cw)/a0; B2 = 1.0f/a0;
        A1 = (-2.0f*cw)/a0; A2 = (1.0f - alpha)/a0;
    }
    const float nF = (float)NS;
    const float invA = 1.0f/(1.0f + envp[0]*0.1f*nF);
    const float invR = 1.0f/(1.0f + envp[2]*0.1f*nF);
    const float sa_ = clipf(envp[1], 0.0f, 1.0f) * h[4];
    float x1 = (c>0)? ws[WS_XT1 + c-1] : 0.0f;
    float x2 = (c>0)? ws[WS_XT2 + c-1] : 0.0f;
    float y1 = ws[WS_BRS + 2*c];
    float y2 = ws[WS_BRS + 2*c+1];
    for (int tt=0; tt<BRL/32; tt++) {
        float4* dst4 = (float4*)(x + base + (long)tt*32);
        for (int q = tid; q < 256*8; q += 256) {
            int r = q >> 3, c4 = q & 7;
            float4 v = ((const float4*)dst4)[(long)r*(BRL/4) + c4];
            tile[r*33 + c4*4 + 0] = v.x;
            tile[r*33 + c4*4 + 1] = v.y;
            tile[r*33 + c4*4 + 2] = v.z;
            tile[r*33 + c4*4 + 3] = v.w;
        }
        __syncthreads();
        #pragma unroll
        for (int j=0;j<32;j++){
            float xv = tile[tid*33 + j];
            float y = B0*xv + B1*x1 + B2*x2 - A1*y1 - A2*y2;
            x2=x1; x1=xv; y2=y1; y1=y;
            int idx = c*BRL + tt*32 + j;
            float ea = fminf((float)idx * invA, 1.0f);
            float er = fminf((float)(NS-1-idx) * invR, 1.0f);
            tile[tid*33 + j] = y * (ea*er*sa_);
        }
        __syncthreads();
        for (int q = tid; q < 256*8; q += 256) {
            int r = q >> 3, c4 = q & 7;
            float4 v;
            v.x = tile[r*33 + c4*4 + 0];
            v.y = tile[r*33 + c4*4 + 1];
            v.z = tile[r*33 + c4*4 + 2];
            v.w = tile[r*33 + c4*4 + 3];
            dst4[(long)r*(BRL/4) + c4] = v;
        }
        __syncthreads();
    }
}

extern "C" void kernel_launch(void* const* d_in, const int* in_sizes, int n_in,
                              void* d_out, int out_size, void* d_ws, size_t ws_size,
                              hipStream_t stream) {
    const float* fb   = (const float*)d_in[0];
    const float* wt   = (const float*)d_in[1];
    const float* h    = (const float*)d_in[2];
    const float* envp = (const float*)d_in[3];
    const float* lp2c = (const float*)d_in[4];
    float* out = (float*)d_out;
    float* ws  = (float*)d_ws;

    hipLaunchKernelGGL(kD_ksA,   dim3(G_CH+1), dim3(448), 0, stream, fb, wt, h, lp2c, ws);
    hipLaunchKernelGGL(kB_scan,  dim3(7),      dim3(64),  0, stream, h, ws);
    hipLaunchKernelGGL(k3_ksC,   dim3(G_CH),   dim3(448), 0, stream, fb, h, ws, out);
    hipLaunchKernelGGL(k4_br1,   dim3(256),    dim3(256), 0, stream, out, h, ws);
    hipLaunchKernelGGL(kP_state, dim3(256),    dim3(256), 0, stream, h, ws);
    hipLaunchKernelGGL(k6_br2,   dim3(256),    dim3(256), 0, stream, out, h, envp, ws);
}